// Round 1
// baseline (395.572 us; speedup 1.0000x reference)
//
#include <hip/hip_runtime.h>
#include <hip/hip_bf16.h>
#include <math.h>

#define SEQ   2048
#define BATCH 2
#define NROWS 4096      /* BATCH*SEQ */
#define DIMM  1024
#define QKV3  3072
#define FFD   4096
#define NHEAD 16
#define DHEAD 64

typedef __bf16 bf16;
typedef __bf16 bf16x8 __attribute__((ext_vector_type(8)));
typedef float  f32x4  __attribute__((ext_vector_type(4)));

static __device__ __forceinline__ f32x4 mfma16(bf16x8 a, bf16x8 b, f32x4 c) {
    return __builtin_amdgcn_mfma_f32_16x16x32_bf16(a, b, c, 0, 0, 0);
}

#define GLDS16(gp, lp) __builtin_amdgcn_global_load_lds( \
    (__attribute__((address_space(1))) void*)(gp),       \
    (__attribute__((address_space(3))) void*)(lp), 16, 0, 0)

// ---------------------------------------------------------------------------
// Transpose + cast: src fp32 [K][N] -> dst bf16 [N][K]
// ---------------------------------------------------------------------------
__global__ __launch_bounds__(256) void tcast_kernel(
    const float* __restrict__ src, bf16* __restrict__ dst, int K, int N)
{
    __shared__ float tile[32][33];
    const int n0 = blockIdx.x * 32;
    const int k0 = blockIdx.y * 32;
    const int r = threadIdx.x >> 5;   // 0..7
    const int c = threadIdx.x & 31;
    #pragma unroll
    for (int i = 0; i < 4; ++i)
        tile[r + 8 * i][c] = src[(size_t)(k0 + r + 8 * i) * N + n0 + c];
    __syncthreads();
    #pragma unroll
    for (int i = 0; i < 4; ++i)
        dst[(size_t)(n0 + r + 8 * i) * K + k0 + c] = (bf16)tile[c][r + 8 * i];
}

// ---------------------------------------------------------------------------
// LayerNorm fp32 [NROWS][1024] -> bf16, one block per row
// ---------------------------------------------------------------------------
__global__ __launch_bounds__(256) void ln_cast_kernel(
    const float* __restrict__ x, const float* __restrict__ g,
    const float* __restrict__ b, bf16* __restrict__ out)
{
    const int row = blockIdx.x;
    const int t = threadIdx.x;
    const float4 v = ((const float4*)(x + (size_t)row * DIMM))[t];
    float s  = v.x + v.y + v.z + v.w;
    float sq = v.x * v.x + v.y * v.y + v.z * v.z + v.w * v.w;
    #pragma unroll
    for (int m = 1; m < 64; m <<= 1) {
        s  += __shfl_xor(s, m, 64);
        sq += __shfl_xor(sq, m, 64);
    }
    __shared__ float ss[4], ssq[4];
    const int wave = t >> 6;
    if ((t & 63) == 0) { ss[wave] = s; ssq[wave] = sq; }
    __syncthreads();
    s  = ss[0] + ss[1] + ss[2] + ss[3];
    sq = ssq[0] + ssq[1] + ssq[2] + ssq[3];
    const float mean = s * (1.0f / DIMM);
    const float var  = sq * (1.0f / DIMM) - mean * mean;
    const float rs   = rsqrtf(var + 1e-5f);
    const float4 gv = ((const float4*)g)[t];
    const float4 bv = ((const float4*)b)[t];
    bf16* o = out + (size_t)row * DIMM + t * 4;
    o[0] = (bf16)((v.x - mean) * rs * gv.x + bv.x);
    o[1] = (bf16)((v.y - mean) * rs * gv.y + bv.y);
    o[2] = (bf16)((v.z - mean) * rs * gv.z + bv.z);
    o[3] = (bf16)((v.w - mean) * rs * gv.w + bv.w);
}

// ---------------------------------------------------------------------------
// bf16 MFMA GEMM (m97 structure): C[M][N] = A[M][K] @ B[K][N], B given as
// BT[N][K]. 128x128 tile, BK=32, 4 waves each computing 64x64 via 4x4 of
// 16x16x32 fragments. global_load_lds width-16 staging, linear LDS.
// EPI: 0 = bf16 out; 1 = +bias +residual, fp32 out; 2 = +bias, GELU, bf16 out
// ---------------------------------------------------------------------------
template<int EPI>
__global__ __launch_bounds__(256, 2)
void gemm_bt_kernel(const bf16* __restrict__ A, const bf16* __restrict__ BT,
                    const float* __restrict__ bias, const float* __restrict__ res,
                    void* __restrict__ Cout, int M, int N, int K)
{
    __shared__ bf16 As[4096];   // [128 m][32 k]
    __shared__ bf16 Bs[4096];   // [128 n][32 k]
    const int nb = N >> 7;
    const int bm = blockIdx.x / nb, bn = blockIdx.x - bm * nb;
    const int tm = bm << 7, tn = bn << 7;
    const int tid = threadIdx.x;
    const int lane = tid & 63, wave = tid >> 6;
    const int wm = (wave >> 1) << 6, wn = (wave & 1) << 6;

    // staging source: wave w, instr j covers tile rows w*32+j*16 .. +15
    const bf16* ga = A  + (size_t)(tm + wave * 32 + (lane >> 2)) * K + ((lane & 3) << 3);
    const bf16* gb = BT + (size_t)(tn + wave * 32 + (lane >> 2)) * K + ((lane & 3) << 3);
    bf16* la = As + wave * 1024;   // wave-uniform LDS dest
    bf16* lb = Bs + wave * 1024;
    const size_t k16 = (size_t)16 * K;

    f32x4 acc[4][4] = {};
    const int ro = (lane & 15) * 32 + ((lane >> 4) << 3);

    for (int k0 = 0; k0 < K; k0 += 32) {
        __syncthreads();
        GLDS16(ga + k0,       la);
        GLDS16(ga + k0 + k16, la + 512);
        GLDS16(gb + k0,       lb);
        GLDS16(gb + k0 + k16, lb + 512);
        __syncthreads();
        bf16x8 af[4], bfr[4];
        #pragma unroll
        for (int i = 0; i < 4; ++i) {
            af[i]  = *(const bf16x8*)(As + (wm + i * 16) * 32 + ro);
            bfr[i] = *(const bf16x8*)(Bs + (wn + i * 16) * 32 + ro);
        }
        #pragma unroll
        for (int i = 0; i < 4; ++i)
            #pragma unroll
            for (int j = 0; j < 4; ++j)
                acc[i][j] = mfma16(af[i], bfr[j], acc[i][j]);
    }

    // C/D layout: col = lane&15, row = (lane>>4)*4 + r   [m89 verified]
    const int r0 = tm + wm + ((lane >> 4) << 2);
    const int c0 = tn + wn + (lane & 15);
    if (EPI == 0) {
        bf16* C = (bf16*)Cout;
        #pragma unroll
        for (int i = 0; i < 4; ++i)
            #pragma unroll
            for (int j = 0; j < 4; ++j)
                #pragma unroll
                for (int r = 0; r < 4; ++r)
                    C[(size_t)(r0 + i * 16 + r) * N + (c0 + j * 16)] = (bf16)acc[i][j][r];
    } else if (EPI == 1) {
        float* C = (float*)Cout;
        #pragma unroll
        for (int j = 0; j < 4; ++j) {
            const float bv = bias[c0 + j * 16];
            #pragma unroll
            for (int i = 0; i < 4; ++i)
                #pragma unroll
                for (int r = 0; r < 4; ++r) {
                    const size_t idx = (size_t)(r0 + i * 16 + r) * N + (c0 + j * 16);
                    C[idx] = acc[i][j][r] + bv + res[idx];
                }
        }
    } else {
        bf16* C = (bf16*)Cout;
        #pragma unroll
        for (int j = 0; j < 4; ++j) {
            const float bv = bias[c0 + j * 16];
            #pragma unroll
            for (int i = 0; i < 4; ++i)
                #pragma unroll
                for (int r = 0; r < 4; ++r) {
                    const float v = acc[i][j][r] + bv;
                    const float gl = 0.5f * v * (1.0f + erff(v * 0.70710678118654752f));
                    C[(size_t)(r0 + i * 16 + r) * N + (c0 + j * 16)] = (bf16)gl;
                }
        }
    }
}

// ---------------------------------------------------------------------------
// Flash attention. Grid (32 qtiles, 32 bh). 4 waves/block, each wave owns 16
// q-rows. K tile [64 kv][64 d] and V^T tile [64 d][64 kv] in LDS, XOR-swizzled
// (byte ^= (row&7)<<4) so all ds_read_b128 are ~conflict-free. Online softmax
// in MFMA accum layout; P via per-wave swizzled LDS round-trip.
// ---------------------------------------------------------------------------
__global__ __launch_bounds__(256, 2)
void attn_kernel(const bf16* __restrict__ qkv, bf16* __restrict__ out)
{
    __shared__ bf16 Ks[64 * 64];
    __shared__ bf16 Vs[64 * 64];
    __shared__ bf16 Ps[4][16 * 64];
    const int qt = blockIdx.x;          // 0..31
    const int bh = blockIdx.y;          // 0..31
    const int b = bh >> 4, h = bh & 15;
    const int tid = threadIdx.x;
    const int lane = tid & 63, wave = tid >> 6;

    const bf16* qbase = qkv + (size_t)(b * SEQ) * QKV3 + h * DHEAD;          // Q region
    const bf16* kbase = qbase + DIMM;                                        // K region
    const bf16* vbase = qbase + 2 * DIMM;                                    // V region

    // Q fragments (A operand), scale 1/8 folded in (exact in bf16)
    const int q0 = qt * 64 + wave * 16;
    bf16x8 qf[2];
    {
        const bf16* qp = qbase + (size_t)(q0 + (lane & 15)) * QKV3 + ((lane >> 4) << 3);
        qf[0] = *(const bf16x8*)qp;
        qf[1] = *(const bf16x8*)(qp + 32);
        #pragma unroll
        for (int j = 0; j < 8; ++j) {
            qf[0][j] = (bf16)((float)qf[0][j] * 0.125f);
            qf[1][j] = (bf16)((float)qf[1][j] * 0.125f);
        }
    }

    float m[4], l[4];
    f32x4 o[4] = {};
    #pragma unroll
    for (int r = 0; r < 4; ++r) { m[r] = -1e30f; l[r] = 0.0f; }

    for (int kt = 0; kt < SEQ; kt += 64) {
        __syncthreads();
        // stage K tile (swizzled rows) and V^T tile (transposed, swizzled)
        #pragma unroll
        for (int it = 0; it < 2; ++it) {
            const int c = it * 256 + tid;        // 512 chunks of 16B
            const int row = c >> 3, o8 = c & 7;
            const bf16x8 k8 = *(const bf16x8*)(kbase + (size_t)(kt + row) * QKV3 + o8 * 8);
            const int kb = ((row * 128) + o8 * 16) ^ ((row & 7) << 4);
            *(bf16x8*)((char*)Ks + kb) = k8;
            const bf16x8 v8 = *(const bf16x8*)(vbase + (size_t)(kt + row) * QKV3 + o8 * 8);
            #pragma unroll
            for (int j = 0; j < 8; ++j) {
                const int d = o8 * 8 + j;
                const int vb = (d * 128 + row * 2) ^ ((d & 7) << 4);
                *(bf16*)((char*)Vs + vb) = v8[j];
            }
        }
        __syncthreads();

        // S = Q K^T  (accum: col=lane&15 -> kv, row=(lane>>4)*4+r -> q)
        f32x4 sv[4];
        #pragma unroll
        for (int kf = 0; kf < 4; ++kf) {
            f32x4 z = {0.f, 0.f, 0.f, 0.f};
            sv[kf] = z;
            #pragma unroll
            for (int ks = 0; ks < 2; ++ks) {
                const int row = kf * 16 + (lane & 15);
                const int bo = (row * 128 + ks * 64 + ((lane >> 4) << 4)) ^ ((row & 7) << 4);
                const bf16x8 kfrag = *(const bf16x8*)((const char*)Ks + bo);
                sv[kf] = mfma16(qf[ks], kfrag, sv[kf]);
            }
        }

        // online softmax, write P (bf16) to per-wave swizzled LDS
        #pragma unroll
        for (int r = 0; r < 4; ++r) {
            float t = fmaxf(fmaxf(sv[0][r], sv[1][r]), fmaxf(sv[2][r], sv[3][r]));
            t = fmaxf(t, __shfl_xor(t, 1, 64));
            t = fmaxf(t, __shfl_xor(t, 2, 64));
            t = fmaxf(t, __shfl_xor(t, 4, 64));
            t = fmaxf(t, __shfl_xor(t, 8, 64));
            const float nm = fmaxf(m[r], t);
            const int qrow = ((lane >> 4) << 2) + r;
            float rowsum = 0.0f;
            #pragma unroll
            for (int kf = 0; kf < 4; ++kf) {
                const float p = __expf(sv[kf][r] - nm);
                rowsum += p;
                const int col = kf * 16 + (lane & 15);
                const int bo = (qrow * 128 + col * 2) ^ ((qrow & 7) << 4);
                *(bf16*)((char*)Ps[wave] + bo) = (bf16)p;
            }
            rowsum += __shfl_xor(rowsum, 1, 64);
            rowsum += __shfl_xor(rowsum, 2, 64);
            rowsum += __shfl_xor(rowsum, 4, 64);
            rowsum += __shfl_xor(rowsum, 8, 64);
            const float fr = __expf(m[r] - nm);
            l[r] = l[r] * fr + rowsum;
            m[r] = nm;
            #pragma unroll
            for (int df = 0; df < 4; ++df) o[df][r] *= fr;
        }

        // PV: O += P[16q x 64kv] @ V[64kv x 64d]
        bf16x8 pf[2];
        #pragma unroll
        for (int ks = 0; ks < 2; ++ks) {
            const int row = lane & 15;
            const int bo = (row * 128 + ks * 64 + ((lane >> 4) << 4)) ^ ((row & 7) << 4);
            pf[ks] = *(const bf16x8*)((const char*)Ps[wave] + bo);
        }
        #pragma unroll
        for (int df = 0; df < 4; ++df)
            #pragma unroll
            for (int ks = 0; ks < 2; ++ks) {
                const int row = df * 16 + (lane & 15);
                const int bo = (row * 128 + ks * 64 + ((lane >> 4) << 4)) ^ ((row & 7) << 4);
                const bf16x8 vfrag = *(const bf16x8*)((const char*)Vs + bo);
                o[df] = mfma16(pf[ks], vfrag, o[df]);
            }
    }

    // epilogue: normalize and store
    #pragma unroll
    for (int r = 0; r < 4; ++r) {
        const float inv = 1.0f / l[r];
        const int grow = b * SEQ + q0 + ((lane >> 4) << 2) + r;
        bf16* op = out + (size_t)grow * DIMM + h * DHEAD + (lane & 15);
        #pragma unroll
        for (int df = 0; df < 4; ++df)
            op[df * 16] = (bf16)(o[df][r] * inv);
    }
}

// ---------------------------------------------------------------------------
extern "C" void kernel_launch(void* const* d_in, const int* in_sizes, int n_in,
                              void* d_out, int out_size, void* d_ws, size_t ws_size,
                              hipStream_t stream)
{
    (void)in_sizes; (void)n_in; (void)out_size; (void)ws_size;
    const float* x    = (const float*)d_in[0];
    const float* ln1g = (const float*)d_in[1];
    const float* ln1b = (const float*)d_in[2];
    const float* ln2g = (const float*)d_in[3];
    const float* ln2b = (const float*)d_in[4];
    const float* wqkv = (const float*)d_in[5];
    const float* wout = (const float*)d_in[6];
    const float* bout = (const float*)d_in[7];
    const float* wff1 = (const float*)d_in[8];
    const float* bff1 = (const float*)d_in[9];
    const float* wff2 = (const float*)d_in[10];
    const float* bff2 = (const float*)d_in[11];

    char* ws = (char*)d_ws;                               // 80 MB used
    bf16*  wqkvT = (bf16*)(ws);                           // [3072][1024]
    bf16*  woutT = (bf16*)(ws + 6291456);                 // [1024][1024]
    bf16*  wff1T = (bf16*)(ws + 8388608);                 // [4096][1024]
    bf16*  wff2T = (bf16*)(ws + 16777216);                // [1024][4096]
    float* x2    = (float*)(ws + 25165824);               // [4096][1024] fp32
    bf16*  hbuf  = (bf16*)(ws + 41943040);                // [4096][1024] (h and h2)
    bf16*  qkvb  = (bf16*)(ws + 50331648);                // [4096][3072]
    bf16*  attnb = (bf16*)(ws + 75497472);                // [4096][1024]
    bf16*  fbuf  = (bf16*)(ws + 50331648);                // [4096][4096], reuses qkv+attn

    const dim3 blk(256);
    // weight transpose+cast (every call: deterministic)
    tcast_kernel<<<dim3(QKV3 / 32, DIMM / 32), blk, 0, stream>>>(wqkv, wqkvT, DIMM, QKV3);
    tcast_kernel<<<dim3(DIMM / 32, DIMM / 32), blk, 0, stream>>>(wout, woutT, DIMM, DIMM);
    tcast_kernel<<<dim3(FFD  / 32, DIMM / 32), blk, 0, stream>>>(wff1, wff1T, DIMM, FFD);
    tcast_kernel<<<dim3(DIMM / 32, FFD  / 32), blk, 0, stream>>>(wff2, wff2T, FFD, DIMM);

    ln_cast_kernel<<<NROWS, blk, 0, stream>>>(x, ln1g, ln1b, hbuf);
    gemm_bt_kernel<0><<<(NROWS / 128) * (QKV3 / 128), blk, 0, stream>>>(
        hbuf, wqkvT, nullptr, nullptr, qkvb, NROWS, QKV3, DIMM);
    attn_kernel<<<dim3(SEQ / 64, BATCH * NHEAD), blk, 0, stream>>>(qkvb, attnb);
    gemm_bt_kernel<1><<<(NROWS / 128) * (DIMM / 128), blk, 0, stream>>>(
        attnb, woutT, bout, x, x2, NROWS, DIMM, DIMM);
    ln_cast_kernel<<<NROWS, blk, 0, stream>>>(x2, ln2g, ln2b, hbuf);
    gemm_bt_kernel<2><<<(NROWS / 128) * (FFD / 128), blk, 0, stream>>>(
        hbuf, wff1T, bff1, nullptr, fbuf, NROWS, FFD, DIMM);
    gemm_bt_kernel<1><<<(NROWS / 128) * (DIMM / 128), blk, 0, stream>>>(
        fbuf, wff2T, bff2, x2, (float*)d_out, NROWS, DIMM, FFD);
}

// Round 2
// 372.501 us; speedup vs baseline: 1.0619x; 1.0619x over previous
//
#include <hip/hip_runtime.h>
#include <hip/hip_bf16.h>
#include <math.h>

#define SEQ   2048
#define BATCH 2
#define NROWS 4096      /* BATCH*SEQ */
#define DIMM  1024
#define QKV3  3072
#define FFD   4096
#define NHEAD 16
#define DHEAD 64

typedef __bf16 bf16;
typedef __bf16 bf16x8 __attribute__((ext_vector_type(8)));
typedef float  f32x4  __attribute__((ext_vector_type(4)));

static __device__ __forceinline__ f32x4 mfma16(bf16x8 a, bf16x8 b, f32x4 c) {
    return __builtin_amdgcn_mfma_f32_16x16x32_bf16(a, b, c, 0, 0, 0);
}

#define GLDS16(gp, lp) __builtin_amdgcn_global_load_lds( \
    (__attribute__((address_space(1))) void*)(gp),       \
    (__attribute__((address_space(3))) void*)(lp), 16, 0, 0)

// ---------------------------------------------------------------------------
// Transpose + cast: src fp32 [K][N] -> dst bf16 [N][K]
// ---------------------------------------------------------------------------
__global__ __launch_bounds__(256) void tcast_kernel(
    const float* __restrict__ src, bf16* __restrict__ dst, int K, int N)
{
    __shared__ float tile[32][33];
    const int n0 = blockIdx.x * 32;
    const int k0 = blockIdx.y * 32;
    const int r = threadIdx.x >> 5;   // 0..7
    const int c = threadIdx.x & 31;
    #pragma unroll
    for (int i = 0; i < 4; ++i)
        tile[r + 8 * i][c] = src[(size_t)(k0 + r + 8 * i) * N + n0 + c];
    __syncthreads();
    #pragma unroll
    for (int i = 0; i < 4; ++i)
        dst[(size_t)(n0 + r + 8 * i) * K + k0 + c] = (bf16)tile[c][r + 8 * i];
}

// ---------------------------------------------------------------------------
// LayerNorm fp32 [NROWS][1024] -> bf16, one block per row
// ---------------------------------------------------------------------------
__global__ __launch_bounds__(256) void ln_cast_kernel(
    const float* __restrict__ x, const float* __restrict__ g,
    const float* __restrict__ b, bf16* __restrict__ out)
{
    const int row = blockIdx.x;
    const int t = threadIdx.x;
    const float4 v = ((const float4*)(x + (size_t)row * DIMM))[t];
    float s  = v.x + v.y + v.z + v.w;
    float sq = v.x * v.x + v.y * v.y + v.z * v.z + v.w * v.w;
    #pragma unroll
    for (int m = 1; m < 64; m <<= 1) {
        s  += __shfl_xor(s, m, 64);
        sq += __shfl_xor(sq, m, 64);
    }
    __shared__ float ss[4], ssq[4];
    const int wave = t >> 6;
    if ((t & 63) == 0) { ss[wave] = s; ssq[wave] = sq; }
    __syncthreads();
    s  = ss[0] + ss[1] + ss[2] + ss[3];
    sq = ssq[0] + ssq[1] + ssq[2] + ssq[3];
    const float mean = s * (1.0f / DIMM);
    const float var  = sq * (1.0f / DIMM) - mean * mean;
    const float rs   = rsqrtf(var + 1e-5f);
    const float4 gv = ((const float4*)g)[t];
    const float4 bv = ((const float4*)b)[t];
    bf16* o = out + (size_t)row * DIMM + t * 4;
    o[0] = (bf16)((v.x - mean) * rs * gv.x + bv.x);
    o[1] = (bf16)((v.y - mean) * rs * gv.y + bv.y);
    o[2] = (bf16)((v.z - mean) * rs * gv.z + bv.z);
    o[3] = (bf16)((v.w - mean) * rs * gv.w + bv.w);
}

// ---------------------------------------------------------------------------
// bf16 MFMA GEMM (m97 structure): C[M][N] = A[M][K] @ B[K][N], B given as
// BT[N][K]. 128x128 tile, BK=32, 4 waves each computing 64x64 via 4x4 of
// 16x16x32 fragments. global_load_lds width-16 staging, linear LDS.
// EPI: 0 = bf16 out; 1 = +bias +residual, fp32 out; 2 = +bias, GELU, bf16 out
// ---------------------------------------------------------------------------
template<int EPI>
__global__ __launch_bounds__(256, 2)
void gemm_bt_kernel(const bf16* __restrict__ A, const bf16* __restrict__ BT,
                    const float* __restrict__ bias, const float* __restrict__ res,
                    void* __restrict__ Cout, int M, int N, int K)
{
    __shared__ bf16 As[4096];   // [128 m][32 k]
    __shared__ bf16 Bs[4096];   // [128 n][32 k]
    const int nb = N >> 7;
    const int bm = blockIdx.x / nb, bn = blockIdx.x - bm * nb;
    const int tm = bm << 7, tn = bn << 7;
    const int tid = threadIdx.x;
    const int lane = tid & 63, wave = tid >> 6;
    const int wm = (wave >> 1) << 6, wn = (wave & 1) << 6;

    const bf16* ga = A  + (size_t)(tm + wave * 32 + (lane >> 2)) * K + ((lane & 3) << 3);
    const bf16* gb = BT + (size_t)(tn + wave * 32 + (lane >> 2)) * K + ((lane & 3) << 3);
    bf16* la = As + wave * 1024;
    bf16* lb = Bs + wave * 1024;
    const size_t k16 = (size_t)16 * K;

    f32x4 acc[4][4] = {};
    const int ro = (lane & 15) * 32 + ((lane >> 4) << 3);

    for (int k0 = 0; k0 < K; k0 += 32) {
        __syncthreads();
        GLDS16(ga + k0,       la);
        GLDS16(ga + k0 + k16, la + 512);
        GLDS16(gb + k0,       lb);
        GLDS16(gb + k0 + k16, lb + 512);
        __syncthreads();
        bf16x8 af[4], bfr[4];
        #pragma unroll
        for (int i = 0; i < 4; ++i) {
            af[i]  = *(const bf16x8*)(As + (wm + i * 16) * 32 + ro);
            bfr[i] = *(const bf16x8*)(Bs + (wn + i * 16) * 32 + ro);
        }
        #pragma unroll
        for (int i = 0; i < 4; ++i)
            #pragma unroll
            for (int j = 0; j < 4; ++j)
                acc[i][j] = mfma16(af[i], bfr[j], acc[i][j]);
    }

    const int r0 = tm + wm + ((lane >> 4) << 2);
    const int c0 = tn + wn + (lane & 15);
    if (EPI == 0) {
        bf16* C = (bf16*)Cout;
        #pragma unroll
        for (int i = 0; i < 4; ++i)
            #pragma unroll
            for (int j = 0; j < 4; ++j)
                #pragma unroll
                for (int r = 0; r < 4; ++r)
                    C[(size_t)(r0 + i * 16 + r) * N + (c0 + j * 16)] = (bf16)acc[i][j][r];
    } else if (EPI == 1) {
        float* C = (float*)Cout;
        #pragma unroll
        for (int j = 0; j < 4; ++j) {
            const float bv = bias[c0 + j * 16];
            #pragma unroll
            for (int i = 0; i < 4; ++i)
                #pragma unroll
                for (int r = 0; r < 4; ++r) {
                    const size_t idx = (size_t)(r0 + i * 16 + r) * N + (c0 + j * 16);
                    C[idx] = acc[i][j][r] + bv + res[idx];
                }
        }
    } else {
        bf16* C = (bf16*)Cout;
        #pragma unroll
        for (int j = 0; j < 4; ++j) {
            const float bv = bias[c0 + j * 16];
            #pragma unroll
            for (int i = 0; i < 4; ++i)
                #pragma unroll
                for (int r = 0; r < 4; ++r) {
                    const float v = acc[i][j][r] + bv;
                    const float gl = 0.5f * v * (1.0f + erff(v * 0.70710678118654752f));
                    C[(size_t)(r0 + i * 16 + r) * N + (c0 + j * 16)] = (bf16)gl;
                }
        }
    }
}

// ---------------------------------------------------------------------------
// V transpose per head: qkv[b][n][2*DIMM + h*64 + d] -> vT[bh][d][n]
// LDS tile [64 n][64 d] with XOR swizzle byte ^= ((n>>3)&7)<<4 so the
// column-gather reads are conflict-free (bank = (d>>1) ^ (nc<<2)).
// ---------------------------------------------------------------------------
__global__ __launch_bounds__(256) void vtrans_kernel(
    const bf16* __restrict__ qkv, bf16* __restrict__ vT)
{
    __shared__ bf16 t[64 * 64];
    const int n0 = blockIdx.x * 64;
    const int bh = blockIdx.y;
    const int b = bh >> 4, h = bh & 15;
    const bf16* src = qkv + (size_t)(b * SEQ + n0) * QKV3 + 2 * DIMM + h * DHEAD;

    #pragma unroll
    for (int it = 0; it < 2; ++it) {
        const int c = it * 256 + threadIdx.x;   // 512 chunks of 8 elems
        const int n = c >> 3, d8 = (c & 7) * 8;
        const bf16x8 v8 = *(const bf16x8*)(src + (size_t)n * QKV3 + d8);
        const int byte = (n * 128 + d8 * 2) ^ (((n >> 3) & 7) << 4);
        *(bf16x8*)((char*)t + byte) = v8;
    }
    __syncthreads();
    #pragma unroll
    for (int it = 0; it < 2; ++it) {
        const int c = it * 256 + threadIdx.x;
        const int d = c >> 3, nc = c & 7;
        bf16x8 o8;
        #pragma unroll
        for (int i = 0; i < 8; ++i) {
            const int n = nc * 8 + i;
            const int byte = (n * 128 + d * 2) ^ ((nc & 7) << 4);
            o8[i] = *(const bf16*)((const char*)t + byte);
        }
        *(bf16x8*)(vT + (size_t)bh * DHEAD * SEQ + (size_t)d * SEQ + n0 + nc * 8) = o8;
    }
}

// ---------------------------------------------------------------------------
// Flash attention v2. Grid (16 qtiles, 32 bh), 4 waves, each wave owns 32
// q-rows (2 m-fragments). K tile [64 kv][64 d] and V^T tile [64 d][64 kv]
// staged via global_load_lds with PRE-SWIZZLED global source so LDS layout is
// byte = (row*128 + col*2) ^ ((row&7)<<4): all ds_read_b128 conflict-free.
// ---------------------------------------------------------------------------
__global__ __launch_bounds__(256, 2)
void attn_kernel(const bf16* __restrict__ qkv, const bf16* __restrict__ vT,
                 bf16* __restrict__ out)
{
    __shared__ bf16 Ks[64 * 64];
    __shared__ bf16 Vs[64 * 64];
    __shared__ bf16 Ps[4][32 * 64];
    const int qt = blockIdx.x;          // 0..15
    const int bh = blockIdx.y;          // 0..31
    const int b = bh >> 4, h = bh & 15;
    const int tid = threadIdx.x;
    const int lane = tid & 63, wave = tid >> 6;

    const bf16* qbase = qkv + (size_t)(b * SEQ) * QKV3 + h * DHEAD;
    const bf16* kbase = qbase + DIMM;
    const bf16* vbase = vT + (size_t)bh * DHEAD * SEQ;

    // Q fragments (A operand), scale 1/8 folded in (exact in bf16)
    const int q0 = qt * 128 + wave * 32;
    bf16x8 qf[2][2];
    #pragma unroll
    for (int mf = 0; mf < 2; ++mf) {
        const bf16* qp = qbase + (size_t)(q0 + mf * 16 + (lane & 15)) * QKV3 + ((lane >> 4) << 3);
        qf[mf][0] = *(const bf16x8*)qp;
        qf[mf][1] = *(const bf16x8*)(qp + 32);
        #pragma unroll
        for (int j = 0; j < 8; ++j) {
            qf[mf][0][j] = (bf16)((float)qf[mf][0][j] * 0.125f);
            qf[mf][1][j] = (bf16)((float)qf[mf][1][j] * 0.125f);
        }
    }

    // staging addresses: wave stages LDS elements [wave*1024, wave*1024+1024)
    // of each tile; lane covers row = wave*16 + s*8 + (lane>>3),
    // swizzled col elems = ((lane&7) ^ (lane>>3)) * 8
    const int srow = lane >> 3;
    const int scol = ((lane & 7) ^ srow) << 3;
    const bf16* gk = kbase + (size_t)(wave * 16 + srow) * QKV3 + scol;
    const bf16* gv = vbase + (size_t)(wave * 16 + srow) * SEQ + scol;
    bf16* lk = Ks + wave * 1024;
    bf16* lv = Vs + wave * 1024;

    float m[2][4], l[2][4];
    f32x4 o[2][4] = {};
    #pragma unroll
    for (int mf = 0; mf < 2; ++mf)
        #pragma unroll
        for (int r = 0; r < 4; ++r) { m[mf][r] = -1e30f; l[mf][r] = 0.0f; }

    for (int kt = 0; kt < SEQ; kt += 64) {
        __syncthreads();
        GLDS16(gk + (size_t)kt * QKV3,             lk);
        GLDS16(gk + (size_t)(kt + 8) * QKV3,       lk + 512);
        GLDS16(gv + kt,                            lv);
        GLDS16(gv + kt + 8 * SEQ,                  lv + 512);
        __syncthreads();

        #pragma unroll
        for (int mf = 0; mf < 2; ++mf) {
            // S = Q K^T : lane holds S[q=mf*16+(lane>>4)*4+r][kv=kf*16+(lane&15)]
            f32x4 sv[4];
            #pragma unroll
            for (int kf = 0; kf < 4; ++kf) {
                f32x4 z = {0.f, 0.f, 0.f, 0.f};
                sv[kf] = z;
                #pragma unroll
                for (int ks = 0; ks < 2; ++ks) {
                    const int row = kf * 16 + (lane & 15);
                    const int bo = (row * 128 + ks * 64 + ((lane >> 4) << 4)) ^ ((row & 7) << 4);
                    const bf16x8 kfrag = *(const bf16x8*)((const char*)Ks + bo);
                    sv[kf] = mfma16(qf[mf][ks], kfrag, sv[kf]);
                }
            }

            // online softmax; P -> per-wave swizzled LDS
            #pragma unroll
            for (int r = 0; r < 4; ++r) {
                float t = fmaxf(fmaxf(sv[0][r], sv[1][r]), fmaxf(sv[2][r], sv[3][r]));
                t = fmaxf(t, __shfl_xor(t, 1, 64));
                t = fmaxf(t, __shfl_xor(t, 2, 64));
                t = fmaxf(t, __shfl_xor(t, 4, 64));
                t = fmaxf(t, __shfl_xor(t, 8, 64));
                const float nm = fmaxf(m[mf][r], t);
                const int qrow = mf * 16 + ((lane >> 4) << 2) + r;
                float rowsum = 0.0f;
                #pragma unroll
                for (int kf = 0; kf < 4; ++kf) {
                    const float p = __expf(sv[kf][r] - nm);
                    rowsum += p;
                    const int col = kf * 16 + (lane & 15);
                    const int bo = (qrow * 128 + col * 2) ^ ((qrow & 7) << 4);
                    *(bf16*)((char*)Ps[wave] + bo) = (bf16)p;
                }
                rowsum += __shfl_xor(rowsum, 1, 64);
                rowsum += __shfl_xor(rowsum, 2, 64);
                rowsum += __shfl_xor(rowsum, 4, 64);
                rowsum += __shfl_xor(rowsum, 8, 64);
                const float fr = __expf(m[mf][r] - nm);
                l[mf][r] = l[mf][r] * fr + rowsum;
                m[mf][r] = nm;
                #pragma unroll
                for (int df = 0; df < 4; ++df) o[mf][df][r] *= fr;
            }

            // PV: O += P[32q x 64kv] @ V[64kv x 64d]
            bf16x8 pf[2];
            #pragma unroll
            for (int ks = 0; ks < 2; ++ks) {
                const int rowp = mf * 16 + (lane & 15);
                const int bo = (rowp * 128 + ks * 64 + ((lane >> 4) << 4)) ^ ((rowp & 7) << 4);
                pf[ks] = *(const bf16x8*)((const char*)Ps[wave] + bo);
            }
            #pragma unroll
            for (int df = 0; df < 4; ++df)
                #pragma unroll
                for (int ks = 0; ks < 2; ++ks) {
                    const int rowv = df * 16 + (lane & 15);
                    const int bo = (rowv * 128 + ks * 64 + ((lane >> 4) << 4)) ^ ((rowv & 7) << 4);
                    const bf16x8 vfrag = *(const bf16x8*)((const char*)Vs + bo);
                    o[mf][df] = mfma16(pf[ks], vfrag, o[mf][df]);
                }
        }
    }

    // epilogue
    #pragma unroll
    for (int mf = 0; mf < 2; ++mf)
        #pragma unroll
        for (int r = 0; r < 4; ++r) {
            const float inv = 1.0f / l[mf][r];
            const int grow = b * SEQ + q0 + mf * 16 + ((lane >> 4) << 2) + r;
            bf16* op = out + (size_t)grow * DIMM + h * DHEAD + (lane & 15);
            #pragma unroll
            for (int df = 0; df < 4; ++df)
                op[df * 16] = (bf16)(o[mf][df][r] * inv);
        }
}

// ---------------------------------------------------------------------------
extern "C" void kernel_launch(void* const* d_in, const int* in_sizes, int n_in,
                              void* d_out, int out_size, void* d_ws, size_t ws_size,
                              hipStream_t stream)
{
    (void)in_sizes; (void)n_in; (void)out_size; (void)ws_size;
    const float* x    = (const float*)d_in[0];
    const float* ln1g = (const float*)d_in[1];
    const float* ln1b = (const float*)d_in[2];
    const float* ln2g = (const float*)d_in[3];
    const float* ln2b = (const float*)d_in[4];
    const float* wqkv = (const float*)d_in[5];
    const float* wout = (const float*)d_in[6];
    const float* bout = (const float*)d_in[7];
    const float* wff1 = (const float*)d_in[8];
    const float* bff1 = (const float*)d_in[9];
    const float* wff2 = (const float*)d_in[10];
    const float* bff2 = (const float*)d_in[11];

    char* ws = (char*)d_ws;
    bf16*  wqkvT = (bf16*)(ws);                           // [3072][1024]      6.0 MB
    bf16*  woutT = (bf16*)(ws + 6291456);                 // [1024][1024]      2.0 MB
    bf16*  wff1T = (bf16*)(ws + 8388608);                 // [4096][1024]      8.0 MB
    bf16*  wff2T = (bf16*)(ws + 16777216);                // [1024][4096]      8.0 MB
    float* x2    = (float*)(ws + 25165824);               // [4096][1024] fp32 (after attn)
    bf16*  vT    = (bf16*)(ws + 25165824);                // [32][64][2048]    8 MB (attn phase only;
                                                          //  x2 written after attn completes... )
    bf16*  hbuf  = (bf16*)(ws + 41943040);                // [4096][1024]
    bf16*  qkvb  = (bf16*)(ws + 50331648);                // [4096][3072]
    bf16*  attnb = (bf16*)(ws + 75497472);                // [4096][1024]
    bf16*  fbuf  = (bf16*)(ws + 50331648);                // [4096][4096]

    const dim3 blk(256);
    tcast_kernel<<<dim3(QKV3 / 32, DIMM / 32), blk, 0, stream>>>(wqkv, wqkvT, DIMM, QKV3);
    tcast_kernel<<<dim3(DIMM / 32, DIMM / 32), blk, 0, stream>>>(wout, woutT, DIMM, DIMM);
    tcast_kernel<<<dim3(FFD  / 32, DIMM / 32), blk, 0, stream>>>(wff1, wff1T, DIMM, FFD);
    tcast_kernel<<<dim3(DIMM / 32, FFD  / 32), blk, 0, stream>>>(wff2, wff2T, FFD, DIMM);

    ln_cast_kernel<<<NROWS, blk, 0, stream>>>(x, ln1g, ln1b, hbuf);
    gemm_bt_kernel<0><<<(NROWS / 128) * (QKV3 / 128), blk, 0, stream>>>(
        hbuf, wqkvT, nullptr, nullptr, qkvb, NROWS, QKV3, DIMM);
    vtrans_kernel<<<dim3(SEQ / 64, BATCH * NHEAD), blk, 0, stream>>>(qkvb, vT);
    attn_kernel<<<dim3(SEQ / 128, BATCH * NHEAD), blk, 0, stream>>>(qkvb, vT, attnb);
    gemm_bt_kernel<1><<<(NROWS / 128) * (DIMM / 128), blk, 0, stream>>>(
        attnb, woutT, bout, x, x2, NROWS, DIMM, DIMM);
    ln_cast_kernel<<<NROWS, blk, 0, stream>>>(x2, ln2g, ln2b, hbuf);
    gemm_bt_kernel<2><<<(NROWS / 128) * (FFD / 128), blk, 0, stream>>>(
        hbuf, wff1T, bff1, nullptr, fbuf, NROWS, FFD, DIMM);
    gemm_bt_kernel<1><<<(NROWS / 128) * (DIMM / 128), blk, 0, stream>>>(
        fbuf, wff2T, bff2, x2, (float*)d_out, NROWS, DIMM, FFD);
}

// Round 3
// 348.700 us; speedup vs baseline: 1.1344x; 1.0683x over previous
//
#include <hip/hip_runtime.h>
#include <hip/hip_bf16.h>
#include <math.h>

#define SEQ   2048
#define BATCH 2
#define NROWS 4096      /* BATCH*SEQ */
#define DIMM  1024
#define QKV3  3072
#define FFD   4096
#define NHEAD 16
#define DHEAD 64

typedef __bf16 bf16;
typedef __bf16 bf16x8 __attribute__((ext_vector_type(8)));
typedef float  f32x4  __attribute__((ext_vector_type(4)));

static __device__ __forceinline__ f32x4 mfma16(bf16x8 a, bf16x8 b, f32x4 c) {
    return __builtin_amdgcn_mfma_f32_16x16x32_bf16(a, b, c, 0, 0, 0);
}

#define GLDS16(gp, lp) __builtin_amdgcn_global_load_lds( \
    (__attribute__((address_space(1))) void*)(gp),       \
    (__attribute__((address_space(3))) void*)(lp), 16, 0, 0)

// ---------------------------------------------------------------------------
// Transpose + cast: src fp32 [K][N] -> dst bf16 [N][K]
// ---------------------------------------------------------------------------
__global__ __launch_bounds__(256) void tcast_kernel(
    const float* __restrict__ src, bf16* __restrict__ dst, int K, int N)
{
    __shared__ float tile[32][33];
    const int n0 = blockIdx.x * 32;
    const int k0 = blockIdx.y * 32;
    const int r = threadIdx.x >> 5;   // 0..7
    const int c = threadIdx.x & 31;
    #pragma unroll
    for (int i = 0; i < 4; ++i)
        tile[r + 8 * i][c] = src[(size_t)(k0 + r + 8 * i) * N + n0 + c];
    __syncthreads();
    #pragma unroll
    for (int i = 0; i < 4; ++i)
        dst[(size_t)(n0 + r + 8 * i) * K + k0 + c] = (bf16)tile[c][r + 8 * i];
}

// ---------------------------------------------------------------------------
// LayerNorm fp32 [NROWS][1024] -> bf16, one block per row
// ---------------------------------------------------------------------------
__global__ __launch_bounds__(256) void ln_cast_kernel(
    const float* __restrict__ x, const float* __restrict__ g,
    const float* __restrict__ b, bf16* __restrict__ out)
{
    const int row = blockIdx.x;
    const int t = threadIdx.x;
    const float4 v = ((const float4*)(x + (size_t)row * DIMM))[t];
    float s  = v.x + v.y + v.z + v.w;
    float sq = v.x * v.x + v.y * v.y + v.z * v.z + v.w * v.w;
    #pragma unroll
    for (int m = 1; m < 64; m <<= 1) {
        s  += __shfl_xor(s, m, 64);
        sq += __shfl_xor(sq, m, 64);
    }
    __shared__ float ss[4], ssq[4];
    const int wave = t >> 6;
    if ((t & 63) == 0) { ss[wave] = s; ssq[wave] = sq; }
    __syncthreads();
    s  = ss[0] + ss[1] + ss[2] + ss[3];
    sq = ssq[0] + ssq[1] + ssq[2] + ssq[3];
    const float mean = s * (1.0f / DIMM);
    const float var  = sq * (1.0f / DIMM) - mean * mean;
    const float rs   = rsqrtf(var + 1e-5f);
    const float4 gv = ((const float4*)g)[t];
    const float4 bv = ((const float4*)b)[t];
    bf16* o = out + (size_t)row * DIMM + t * 4;
    o[0] = (bf16)((v.x - mean) * rs * gv.x + bv.x);
    o[1] = (bf16)((v.y - mean) * rs * gv.y + bv.y);
    o[2] = (bf16)((v.z - mean) * rs * gv.z + bv.z);
    o[3] = (bf16)((v.w - mean) * rs * gv.w + bv.w);
}

// ---------------------------------------------------------------------------
// bf16 MFMA GEMM (m97 structure): C[M][N] = A[M][K] @ B[K][N], B given as
// BT[N][K]. 128x128 tile, BK=32, 4 waves each computing 64x64 via 4x4 of
// 16x16x32 fragments. global_load_lds width-16 staging, linear LDS.
// EPI: 0 = bf16 out; 1 = +bias +residual, fp32 out; 2 = +bias, GELU, bf16 out
// ---------------------------------------------------------------------------
template<int EPI>
__global__ __launch_bounds__(256, 2)
void gemm_bt_kernel(const bf16* __restrict__ A, const bf16* __restrict__ BT,
                    const float* __restrict__ bias, const float* __restrict__ res,
                    void* __restrict__ Cout, int M, int N, int K)
{
    __shared__ bf16 As[4096];   // [128 m][32 k]
    __shared__ bf16 Bs[4096];   // [128 n][32 k]
    const int nb = N >> 7;
    const int bm = blockIdx.x / nb, bn = blockIdx.x - bm * nb;
    const int tm = bm << 7, tn = bn << 7;
    const int tid = threadIdx.x;
    const int lane = tid & 63, wave = tid >> 6;
    const int wm = (wave >> 1) << 6, wn = (wave & 1) << 6;

    const bf16* ga = A  + (size_t)(tm + wave * 32 + (lane >> 2)) * K + ((lane & 3) << 3);
    const bf16* gb = BT + (size_t)(tn + wave * 32 + (lane >> 2)) * K + ((lane & 3) << 3);
    bf16* la = As + wave * 1024;
    bf16* lb = Bs + wave * 1024;
    const size_t k16 = (size_t)16 * K;

    f32x4 acc[4][4] = {};
    const int ro = (lane & 15) * 32 + ((lane >> 4) << 3);

    for (int k0 = 0; k0 < K; k0 += 32) {
        __syncthreads();
        GLDS16(ga + k0,       la);
        GLDS16(ga + k0 + k16, la + 512);
        GLDS16(gb + k0,       lb);
        GLDS16(gb + k0 + k16, lb + 512);
        __syncthreads();
        bf16x8 af[4], bfr[4];
        #pragma unroll
        for (int i = 0; i < 4; ++i) {
            af[i]  = *(const bf16x8*)(As + (wm + i * 16) * 32 + ro);
            bfr[i] = *(const bf16x8*)(Bs + (wn + i * 16) * 32 + ro);
        }
        #pragma unroll
        for (int i = 0; i < 4; ++i)
            #pragma unroll
            for (int j = 0; j < 4; ++j)
                acc[i][j] = mfma16(af[i], bfr[j], acc[i][j]);
    }

    const int r0 = tm + wm + ((lane >> 4) << 2);
    const int c0 = tn + wn + (lane & 15);
    if (EPI == 0) {
        bf16* C = (bf16*)Cout;
        #pragma unroll
        for (int i = 0; i < 4; ++i)
            #pragma unroll
            for (int j = 0; j < 4; ++j)
                #pragma unroll
                for (int r = 0; r < 4; ++r)
                    C[(size_t)(r0 + i * 16 + r) * N + (c0 + j * 16)] = (bf16)acc[i][j][r];
    } else if (EPI == 1) {
        float* C = (float*)Cout;
        #pragma unroll
        for (int j = 0; j < 4; ++j) {
            const float bv = bias[c0 + j * 16];
            #pragma unroll
            for (int i = 0; i < 4; ++i)
                #pragma unroll
                for (int r = 0; r < 4; ++r) {
                    const size_t idx = (size_t)(r0 + i * 16 + r) * N + (c0 + j * 16);
                    C[idx] = acc[i][j][r] + bv + res[idx];
                }
        }
    } else {
        bf16* C = (bf16*)Cout;
        #pragma unroll
        for (int j = 0; j < 4; ++j) {
            const float bv = bias[c0 + j * 16];
            #pragma unroll
            for (int i = 0; i < 4; ++i)
                #pragma unroll
                for (int r = 0; r < 4; ++r) {
                    const float v = acc[i][j][r] + bv;
                    const float gl = 0.5f * v * (1.0f + erff(v * 0.70710678118654752f));
                    C[(size_t)(r0 + i * 16 + r) * N + (c0 + j * 16)] = (bf16)gl;
                }
        }
    }
}

// ---------------------------------------------------------------------------
// V transpose per head: qkv[b][n][2*DIMM + h*64 + d] -> vT[bh][d][n]
// ---------------------------------------------------------------------------
__global__ __launch_bounds__(256) void vtrans_kernel(
    const bf16* __restrict__ qkv, bf16* __restrict__ vT)
{
    __shared__ bf16 t[64 * 64];
    const int n0 = blockIdx.x * 64;
    const int bh = blockIdx.y;
    const int b = bh >> 4, h = bh & 15;
    const bf16* src = qkv + (size_t)(b * SEQ + n0) * QKV3 + 2 * DIMM + h * DHEAD;

    #pragma unroll
    for (int it = 0; it < 2; ++it) {
        const int c = it * 256 + threadIdx.x;   // 512 chunks of 8 elems
        const int n = c >> 3, d8 = (c & 7) * 8;
        const bf16x8 v8 = *(const bf16x8*)(src + (size_t)n * QKV3 + d8);
        const int byte = (n * 128 + d8 * 2) ^ (((n >> 3) & 7) << 4);
        *(bf16x8*)((char*)t + byte) = v8;
    }
    __syncthreads();
    #pragma unroll
    for (int it = 0; it < 2; ++it) {
        const int c = it * 256 + threadIdx.x;
        const int d = c >> 3, nc = c & 7;
        bf16x8 o8;
        #pragma unroll
        for (int i = 0; i < 8; ++i) {
            const int n = nc * 8 + i;
            const int byte = (n * 128 + d * 2) ^ ((nc & 7) << 4);
            o8[i] = *(const bf16*)((const char*)t + byte);
        }
        *(bf16x8*)(vT + (size_t)bh * DHEAD * SEQ + (size_t)d * SEQ + n0 + nc * 8) = o8;
    }
}

// ---------------------------------------------------------------------------
// Flash attention v3. 1-D grid of 512 blocks, XCD-swizzled so each XCD owns
// 4 consecutive (b,h) groups (K/V working set 2 MB < 4 MB per-XCD L2).
// Double-buffered K/V staging: STAGE(kt+1) issued fire-and-forget before
// compute(kt); the NEXT iteration's __syncthreads (vmcnt(0)+barrier) drains
// it, so the load has the whole compute phase to land (T3 minimum 2-phase).
// Defer-max online softmax (T13, THR=8). setprio around MFMA clusters (T5).
// ---------------------------------------------------------------------------
__global__ __launch_bounds__(256, 2)
void attn_kernel(const bf16* __restrict__ qkv, const bf16* __restrict__ vT,
                 bf16* __restrict__ out)
{
    __shared__ bf16 Ks[2][64 * 64];
    __shared__ bf16 Vs[2][64 * 64];
    __shared__ bf16 Ps[4][32 * 64];
    const int bid = blockIdx.x;                 // 0..511
    const int idx = (bid & 7) * 64 + (bid >> 3);  // bijective XCD swizzle
    const int qt = idx & 15;
    const int bh = idx >> 4;
    const int b = bh >> 4, h = bh & 15;
    const int tid = threadIdx.x;
    const int lane = tid & 63, wave = tid >> 6;

    const bf16* qbase = qkv + (size_t)(b * SEQ) * QKV3 + h * DHEAD;
    const bf16* kbase = qbase + DIMM;
    const bf16* vbase = vT + (size_t)bh * DHEAD * SEQ;

    // Q fragments (A operand), scale 1/8 folded in (exact in bf16)
    const int q0 = qt * 128 + wave * 32;
    bf16x8 qf[2][2];
    #pragma unroll
    for (int mf = 0; mf < 2; ++mf) {
        const bf16* qp = qbase + (size_t)(q0 + mf * 16 + (lane & 15)) * QKV3 + ((lane >> 4) << 3);
        qf[mf][0] = *(const bf16x8*)qp;
        qf[mf][1] = *(const bf16x8*)(qp + 32);
        #pragma unroll
        for (int j = 0; j < 8; ++j) {
            qf[mf][0][j] = (bf16)((float)qf[mf][0][j] * 0.125f);
            qf[mf][1][j] = (bf16)((float)qf[mf][1][j] * 0.125f);
        }
    }

    // staging addresses: wave stages LDS elements [wave*1024, +1024) of each
    // tile; lane covers row = wave*16 + (lane>>3) (+8 for 2nd glds),
    // pre-swizzled col = ((lane&7) ^ (lane>>3)) * 8
    const int srow = lane >> 3;
    const int scol = ((lane & 7) ^ srow) << 3;
    const bf16* gk = kbase + (size_t)(wave * 16 + srow) * QKV3 + scol;
    const bf16* gv = vbase + (size_t)(wave * 16 + srow) * SEQ + scol;

#define STAGE(BUF, KT) do {                                        \
        bf16* lk_ = &Ks[BUF][wave * 1024];                         \
        bf16* lv_ = &Vs[BUF][wave * 1024];                         \
        GLDS16(gk + (size_t)(KT) * QKV3,       lk_);               \
        GLDS16(gk + (size_t)((KT) + 8) * QKV3, lk_ + 512);         \
        GLDS16(gv + (KT),                      lv_);               \
        GLDS16(gv + (KT) + 8 * SEQ,            lv_ + 512);         \
    } while (0)

    float m[2][4], l[2][4];
    f32x4 o[2][4] = {};
    #pragma unroll
    for (int mf = 0; mf < 2; ++mf)
        #pragma unroll
        for (int r = 0; r < 4; ++r) { m[mf][r] = -1e30f; l[mf][r] = 0.0f; }

    STAGE(0, 0);
    int cur = 0;
    for (int kt = 0; kt < SEQ; kt += 64) {
        __syncthreads();   // drains vmcnt(0): STAGE(kt) resident for all waves;
                           // also: everyone done reading buf cur^1 -> safe to stage
        if (kt + 64 < SEQ) STAGE(cur ^ 1, kt + 64);   // fire-and-forget

        #pragma unroll
        for (int mf = 0; mf < 2; ++mf) {
            // S = Q K^T : lane holds S[q=mf*16+(lane>>4)*4+r][kv=kf*16+(lane&15)]
            f32x4 sv[4];
            __builtin_amdgcn_s_setprio(1);
            #pragma unroll
            for (int kf = 0; kf < 4; ++kf) {
                f32x4 z = {0.f, 0.f, 0.f, 0.f};
                sv[kf] = z;
                #pragma unroll
                for (int ks = 0; ks < 2; ++ks) {
                    const int row = kf * 16 + (lane & 15);
                    const int bo = (row * 128 + ks * 64 + ((lane >> 4) << 4)) ^ ((row & 7) << 4);
                    const bf16x8 kfrag = *(const bf16x8*)((const char*)&Ks[cur][0] + bo);
                    sv[kf] = mfma16(qf[mf][ks], kfrag, sv[kf]);
                }
            }
            __builtin_amdgcn_s_setprio(0);

            // row maxes + defer-max gate (THR=8)
            float tmax[4];
            float dmax = -3e38f;
            #pragma unroll
            for (int r = 0; r < 4; ++r) {
                float t = fmaxf(fmaxf(sv[0][r], sv[1][r]), fmaxf(sv[2][r], sv[3][r]));
                t = fmaxf(t, __shfl_xor(t, 1, 64));
                t = fmaxf(t, __shfl_xor(t, 2, 64));
                t = fmaxf(t, __shfl_xor(t, 4, 64));
                t = fmaxf(t, __shfl_xor(t, 8, 64));
                tmax[r] = t;
                dmax = fmaxf(dmax, t - m[mf][r]);
            }
            if (__any(dmax > 8.0f)) {
                #pragma unroll
                for (int r = 0; r < 4; ++r) {
                    const float nm = fmaxf(m[mf][r], tmax[r]);
                    const float fr = __expf(m[mf][r] - nm);
                    l[mf][r] *= fr;
                    m[mf][r] = nm;
                    #pragma unroll
                    for (int df = 0; df < 4; ++df) o[mf][df][r] *= fr;
                }
            }
            // P = exp(S - m), write to per-wave swizzled LDS, accumulate l
            #pragma unroll
            for (int r = 0; r < 4; ++r) {
                const int qrow = mf * 16 + ((lane >> 4) << 2) + r;
                float rowsum = 0.0f;
                #pragma unroll
                for (int kf = 0; kf < 4; ++kf) {
                    const float p = __expf(sv[kf][r] - m[mf][r]);
                    rowsum += p;
                    const int col = kf * 16 + (lane & 15);
                    const int bo = (qrow * 128 + col * 2) ^ ((qrow & 7) << 4);
                    *(bf16*)((char*)Ps[wave] + bo) = (bf16)p;
                }
                rowsum += __shfl_xor(rowsum, 1, 64);
                rowsum += __shfl_xor(rowsum, 2, 64);
                rowsum += __shfl_xor(rowsum, 4, 64);
                rowsum += __shfl_xor(rowsum, 8, 64);
                l[mf][r] += rowsum;
            }

            // PV: O += P[32q x 64kv] @ V[64kv x 64d]
            bf16x8 pf[2];
            #pragma unroll
            for (int ks = 0; ks < 2; ++ks) {
                const int rowp = mf * 16 + (lane & 15);
                const int bo = (rowp * 128 + ks * 64 + ((lane >> 4) << 4)) ^ ((rowp & 7) << 4);
                pf[ks] = *(const bf16x8*)((const char*)Ps[wave] + bo);
            }
            __builtin_amdgcn_s_setprio(1);
            #pragma unroll
            for (int df = 0; df < 4; ++df)
                #pragma unroll
                for (int ks = 0; ks < 2; ++ks) {
                    const int rowv = df * 16 + (lane & 15);
                    const int bo = (rowv * 128 + ks * 64 + ((lane >> 4) << 4)) ^ ((rowv & 7) << 4);
                    const bf16x8 vfrag = *(const bf16x8*)((const char*)&Vs[cur][0] + bo);
                    o[mf][df] = mfma16(pf[ks], vfrag, o[mf][df]);
                }
            __builtin_amdgcn_s_setprio(0);
        }
        cur ^= 1;
    }
#undef STAGE

    // epilogue
    #pragma unroll
    for (int mf = 0; mf < 2; ++mf)
        #pragma unroll
        for (int r = 0; r < 4; ++r) {
            const float inv = 1.0f / l[mf][r];
            const int grow = b * SEQ + q0 + mf * 16 + ((lane >> 4) << 2) + r;
            bf16* op = out + (size_t)grow * DIMM + h * DHEAD + (lane & 15);
            #pragma unroll
            for (int df = 0; df < 4; ++df)
                op[df * 16] = (bf16)(o[mf][df][r] * inv);
        }
}

// ---------------------------------------------------------------------------
extern "C" void kernel_launch(void* const* d_in, const int* in_sizes, int n_in,
                              void* d_out, int out_size, void* d_ws, size_t ws_size,
                              hipStream_t stream)
{
    (void)in_sizes; (void)n_in; (void)out_size; (void)ws_size;
    const float* x    = (const float*)d_in[0];
    const float* ln1g = (const float*)d_in[1];
    const float* ln1b = (const float*)d_in[2];
    const float* ln2g = (const float*)d_in[3];
    const float* ln2b = (const float*)d_in[4];
    const float* wqkv = (const float*)d_in[5];
    const float* wout = (const float*)d_in[6];
    const float* bout = (const float*)d_in[7];
    const float* wff1 = (const float*)d_in[8];
    const float* bff1 = (const float*)d_in[9];
    const float* wff2 = (const float*)d_in[10];
    const float* bff2 = (const float*)d_in[11];

    char* ws = (char*)d_ws;
    bf16*  wqkvT = (bf16*)(ws);                           // [3072][1024]      6.0 MB
    bf16*  woutT = (bf16*)(ws + 6291456);                 // [1024][1024]      2.0 MB
    bf16*  wff1T = (bf16*)(ws + 8388608);                 // [4096][1024]      8.0 MB
    bf16*  wff2T = (bf16*)(ws + 16777216);                // [1024][4096]      8.0 MB
    float* x2    = (float*)(ws + 25165824);               // [4096][1024] fp32 (after attn)
    bf16*  vT    = (bf16*)(ws + 25165824);                // [32][64][2048]    8 MB (attn phase only)
    bf16*  hbuf  = (bf16*)(ws + 41943040);                // [4096][1024]
    bf16*  qkvb  = (bf16*)(ws + 50331648);                // [4096][3072]
    bf16*  attnb = (bf16*)(ws + 75497472);                // [4096][1024]
    bf16*  fbuf  = (bf16*)(ws + 50331648);                // [4096][4096]

    const dim3 blk(256);
    tcast_kernel<<<dim3(QKV3 / 32, DIMM / 32), blk, 0, stream>>>(wqkv, wqkvT, DIMM, QKV3);
    tcast_kernel<<<dim3(DIMM / 32, DIMM / 32), blk, 0, stream>>>(wout, woutT, DIMM, DIMM);
    tcast_kernel<<<dim3(FFD  / 32, DIMM / 32), blk, 0, stream>>>(wff1, wff1T, DIMM, FFD);
    tcast_kernel<<<dim3(DIMM / 32, FFD  / 32), blk, 0, stream>>>(wff2, wff2T, FFD, DIMM);

    ln_cast_kernel<<<NROWS, blk, 0, stream>>>(x, ln1g, ln1b, hbuf);
    gemm_bt_kernel<0><<<(NROWS / 128) * (QKV3 / 128), blk, 0, stream>>>(
        hbuf, wqkvT, nullptr, nullptr, qkvb, NROWS, QKV3, DIMM);
    vtrans_kernel<<<dim3(SEQ / 64, BATCH * NHEAD), blk, 0, stream>>>(qkvb, vT);
    attn_kernel<<<dim3(512), blk, 0, stream>>>(qkvb, vT, attnb);
    gemm_bt_kernel<1><<<(NROWS / 128) * (DIMM / 128), blk, 0, stream>>>(
        attnb, woutT, bout, x, x2, NROWS, DIMM, DIMM);
    ln_cast_kernel<<<NROWS, blk, 0, stream>>>(x2, ln2g, ln2b, hbuf);
    gemm_bt_kernel<2><<<(NROWS / 128) * (FFD / 128), blk, 0, stream>>>(
        hbuf, wff1T, bff1, nullptr, fbuf, NROWS, FFD, DIMM);
    gemm_bt_kernel<1><<<(NROWS / 128) * (DIMM / 128), blk, 0, stream>>>(
        fbuf, wff2T, bff2, x2, (float*)d_out, NROWS, DIMM, FFD);
}

// Round 4
// 311.484 us; speedup vs baseline: 1.2700x; 1.1195x over previous
//
#include <hip/hip_runtime.h>
#include <hip/hip_bf16.h>
#include <math.h>

#define SEQ   2048
#define BATCH 2
#define NROWS 4096      /* BATCH*SEQ */
#define DIMM  1024
#define QKV3  3072
#define FFD   4096
#define NHEAD 16
#define DHEAD 64

typedef __bf16 bf16;
typedef __bf16 bf16x4 __attribute__((ext_vector_type(4)));
typedef __bf16 bf16x8 __attribute__((ext_vector_type(8)));
typedef float  f32x4  __attribute__((ext_vector_type(4)));

static __device__ __forceinline__ f32x4 mfma16(bf16x8 a, bf16x8 b, f32x4 c) {
    return __builtin_amdgcn_mfma_f32_16x16x32_bf16(a, b, c, 0, 0, 0);
}

#define GLDS16(gp, lp) __builtin_amdgcn_global_load_lds( \
    (__attribute__((address_space(1))) void*)(gp),       \
    (__attribute__((address_space(3))) void*)(lp), 16, 0, 0)

// ---------------------------------------------------------------------------
// Transpose + cast: src fp32 [K][N] -> dst bf16 [N][K]
// ---------------------------------------------------------------------------
__global__ __launch_bounds__(256) void tcast_kernel(
    const float* __restrict__ src, bf16* __restrict__ dst, int K, int N)
{
    __shared__ float tile[32][33];
    const int n0 = blockIdx.x * 32;
    const int k0 = blockIdx.y * 32;
    const int r = threadIdx.x >> 5;   // 0..7
    const int c = threadIdx.x & 31;
    #pragma unroll
    for (int i = 0; i < 4; ++i)
        tile[r + 8 * i][c] = src[(size_t)(k0 + r + 8 * i) * N + n0 + c];
    __syncthreads();
    #pragma unroll
    for (int i = 0; i < 4; ++i)
        dst[(size_t)(n0 + r + 8 * i) * K + k0 + c] = (bf16)tile[c][r + 8 * i];
}

// ---------------------------------------------------------------------------
// LayerNorm fp32 [NROWS][1024] -> bf16, one block per row
// ---------------------------------------------------------------------------
__global__ __launch_bounds__(256) void ln_cast_kernel(
    const float* __restrict__ x, const float* __restrict__ g,
    const float* __restrict__ b, bf16* __restrict__ out)
{
    const int row = blockIdx.x;
    const int t = threadIdx.x;
    const float4 v = ((const float4*)(x + (size_t)row * DIMM))[t];
    float s  = v.x + v.y + v.z + v.w;
    float sq = v.x * v.x + v.y * v.y + v.z * v.z + v.w * v.w;
    #pragma unroll
    for (int m = 1; m < 64; m <<= 1) {
        s  += __shfl_xor(s, m, 64);
        sq += __shfl_xor(sq, m, 64);
    }
    __shared__ float ss[4], ssq[4];
    const int wave = t >> 6;
    if ((t & 63) == 0) { ss[wave] = s; ssq[wave] = sq; }
    __syncthreads();
    s  = ss[0] + ss[1] + ss[2] + ss[3];
    sq = ssq[0] + ssq[1] + ssq[2] + ssq[3];
    const float mean = s * (1.0f / DIMM);
    const float var  = sq * (1.0f / DIMM) - mean * mean;
    const float rs   = rsqrtf(var + 1e-5f);
    const float4 gv = ((const float4*)g)[t];
    const float4 bv = ((const float4*)b)[t];
    bf16* o = out + (size_t)row * DIMM + t * 4;
    o[0] = (bf16)((v.x - mean) * rs * gv.x + bv.x);
    o[1] = (bf16)((v.y - mean) * rs * gv.y + bv.y);
    o[2] = (bf16)((v.z - mean) * rs * gv.z + bv.z);
    o[3] = (bf16)((v.w - mean) * rs * gv.w + bv.w);
}

// ---------------------------------------------------------------------------
// bf16 MFMA GEMM (m97 structure): C[M][N] = A[M][K] @ B[K][N], B given as
// BT[N][K]. 128x128 tile, BK=32, 4 waves each computing 64x64 via 4x4 of
// 16x16x32 fragments. global_load_lds width-16 staging, linear LDS.
// EPI: 0 = bf16 out; 1 = +bias +residual, fp32 out; 2 = +bias, GELU, bf16 out
// ---------------------------------------------------------------------------
template<int EPI>
__global__ __launch_bounds__(256, 2)
void gemm_bt_kernel(const bf16* __restrict__ A, const bf16* __restrict__ BT,
                    const float* __restrict__ bias, const float* __restrict__ res,
                    void* __restrict__ Cout, int M, int N, int K)
{
    __shared__ bf16 As[4096];   // [128 m][32 k]
    __shared__ bf16 Bs[4096];   // [128 n][32 k]
    const int nb = N >> 7;
    const int bm = blockIdx.x / nb, bn = blockIdx.x - bm * nb;
    const int tm = bm << 7, tn = bn << 7;
    const int tid = threadIdx.x;
    const int lane = tid & 63, wave = tid >> 6;
    const int wm = (wave >> 1) << 6, wn = (wave & 1) << 6;

    const bf16* ga = A  + (size_t)(tm + wave * 32 + (lane >> 2)) * K + ((lane & 3) << 3);
    const bf16* gb = BT + (size_t)(tn + wave * 32 + (lane >> 2)) * K + ((lane & 3) << 3);
    bf16* la = As + wave * 1024;
    bf16* lb = Bs + wave * 1024;
    const size_t k16 = (size_t)16 * K;

    f32x4 acc[4][4] = {};
    const int ro = (lane & 15) * 32 + ((lane >> 4) << 3);

    for (int k0 = 0; k0 < K; k0 += 32) {
        __syncthreads();
        GLDS16(ga + k0,       la);
        GLDS16(ga + k0 + k16, la + 512);
        GLDS16(gb + k0,       lb);
        GLDS16(gb + k0 + k16, lb + 512);
        __syncthreads();
        bf16x8 af[4], bfr[4];
        #pragma unroll
        for (int i = 0; i < 4; ++i) {
            af[i]  = *(const bf16x8*)(As + (wm + i * 16) * 32 + ro);
            bfr[i] = *(const bf16x8*)(Bs + (wn + i * 16) * 32 + ro);
        }
        #pragma unroll
        for (int i = 0; i < 4; ++i)
            #pragma unroll
            for (int j = 0; j < 4; ++j)
                acc[i][j] = mfma16(af[i], bfr[j], acc[i][j]);
    }

    const int r0 = tm + wm + ((lane >> 4) << 2);
    const int c0 = tn + wn + (lane & 15);
    if (EPI == 0) {
        bf16* C = (bf16*)Cout;
        #pragma unroll
        for (int i = 0; i < 4; ++i)
            #pragma unroll
            for (int j = 0; j < 4; ++j)
                #pragma unroll
                for (int r = 0; r < 4; ++r)
                    C[(size_t)(r0 + i * 16 + r) * N + (c0 + j * 16)] = (bf16)acc[i][j][r];
    } else if (EPI == 1) {
        float* C = (float*)Cout;
        #pragma unroll
        for (int j = 0; j < 4; ++j) {
            const float bv = bias[c0 + j * 16];
            #pragma unroll
            for (int i = 0; i < 4; ++i)
                #pragma unroll
                for (int r = 0; r < 4; ++r) {
                    const size_t idx = (size_t)(r0 + i * 16 + r) * N + (c0 + j * 16);
                    C[idx] = acc[i][j][r] + bv + res[idx];
                }
        }
    } else {
        bf16* C = (bf16*)Cout;
        #pragma unroll
        for (int j = 0; j < 4; ++j) {
            const float bv = bias[c0 + j * 16];
            #pragma unroll
            for (int i = 0; i < 4; ++i)
                #pragma unroll
                for (int r = 0; r < 4; ++r) {
                    const float v = acc[i][j][r] + bv;
                    const float gl = 0.5f * v * (1.0f + erff(v * 0.70710678118654752f));
                    C[(size_t)(r0 + i * 16 + r) * N + (c0 + j * 16)] = (bf16)gl;
                }
        }
    }
}

// ---------------------------------------------------------------------------
// V transpose per head: qkv[b][n][2*DIMM + h*64 + d] -> vT[bh][d][n]
// ---------------------------------------------------------------------------
__global__ __launch_bounds__(256) void vtrans_kernel(
    const bf16* __restrict__ qkv, bf16* __restrict__ vT)
{
    __shared__ bf16 t[64 * 64];
    const int n0 = blockIdx.x * 64;
    const int bh = blockIdx.y;
    const int b = bh >> 4, h = bh & 15;
    const bf16* src = qkv + (size_t)(b * SEQ + n0) * QKV3 + 2 * DIMM + h * DHEAD;

    #pragma unroll
    for (int it = 0; it < 2; ++it) {
        const int c = it * 256 + threadIdx.x;   // 512 chunks of 8 elems
        const int n = c >> 3, d8 = (c & 7) * 8;
        const bf16x8 v8 = *(const bf16x8*)(src + (size_t)n * QKV3 + d8);
        const int byte = (n * 128 + d8 * 2) ^ (((n >> 3) & 7) << 4);
        *(bf16x8*)((char*)t + byte) = v8;
    }
    __syncthreads();
    #pragma unroll
    for (int it = 0; it < 2; ++it) {
        const int c = it * 256 + threadIdx.x;
        const int d = c >> 3, nc = c & 7;
        bf16x8 o8;
        #pragma unroll
        for (int i = 0; i < 8; ++i) {
            const int n = nc * 8 + i;
            const int byte = (n * 128 + d * 2) ^ ((nc & 7) << 4);
            o8[i] = *(const bf16*)((const char*)t + byte);
        }
        *(bf16x8*)(vT + (size_t)bh * DHEAD * SEQ + (size_t)d * SEQ + n0 + nc * 8) = o8;
    }
}

// ---------------------------------------------------------------------------
// Flash attention v4: SWAPPED-OPERAND structure.
//   S^T = mfma(K, Q): lane owns one q-row (q = lane&15), 16 kv values in regs
//     -> row max/sum are in-register trees + 2 shfl (was 32 shfl / mf).
//   P: packed bf16x4, 4 ds_write_b64 per mf (was 16 scalar b16 writes).
//   O^T = mfma(V, P): o/m/l all keyed by q = lane&15 -> lane-local rescale.
// K/V double-buffered via global_load_lds with pre-swizzled source (r2);
// XCD-swizzled grid (r3); defer-max THR=8 (T13); setprio on MFMA (T5).
// ---------------------------------------------------------------------------
__global__ __launch_bounds__(256, 2)
void attn_kernel(const bf16* __restrict__ qkv, const bf16* __restrict__ vT,
                 bf16* __restrict__ out)
{
    __shared__ bf16 Ks[2][64 * 64];
    __shared__ bf16 Vs[2][64 * 64];
    __shared__ bf16 Ps[4][32 * 64];
    const int bid = blockIdx.x;                   // 0..511
    const int idx = (bid & 7) * 64 + (bid >> 3);  // bijective XCD swizzle
    const int qt = idx & 15;
    const int bh = idx >> 4;
    const int b = bh >> 4, h = bh & 15;
    const int tid = threadIdx.x;
    const int lane = tid & 63, wave = tid >> 6;
    const int q = lane & 15, hi = lane >> 4;

    const bf16* qbase = qkv + (size_t)(b * SEQ) * QKV3 + h * DHEAD;
    const bf16* kbase = qbase + DIMM;
    const bf16* vbase = vT + (size_t)bh * DHEAD * SEQ;

    // Q fragments (B operand: col q = lane&15, k-slots hi*8+j), scale 1/8
    const int q0 = qt * 128 + wave * 32;
    bf16x8 qf[2][2];
    #pragma unroll
    for (int mf = 0; mf < 2; ++mf) {
        const bf16* qp = qbase + (size_t)(q0 + mf * 16 + q) * QKV3 + (hi << 3);
        qf[mf][0] = *(const bf16x8*)qp;
        qf[mf][1] = *(const bf16x8*)(qp + 32);
        #pragma unroll
        for (int j = 0; j < 8; ++j) {
            qf[mf][0][j] = (bf16)((float)qf[mf][0][j] * 0.125f);
            qf[mf][1][j] = (bf16)((float)qf[mf][1][j] * 0.125f);
        }
    }

    // staging: wave stages LDS elems [wave*1024, +1024); pre-swizzled source
    const int srow = lane >> 3;
    const int scol = ((lane & 7) ^ srow) << 3;
    const bf16* gk = kbase + (size_t)(wave * 16 + srow) * QKV3 + scol;
    const bf16* gv = vbase + (size_t)(wave * 16 + srow) * SEQ + scol;

#define STAGE(BUF, KT) do {                                        \
        bf16* lk_ = &Ks[BUF][wave * 1024];                         \
        bf16* lv_ = &Vs[BUF][wave * 1024];                         \
        GLDS16(gk + (size_t)(KT) * QKV3,       lk_);               \
        GLDS16(gk + (size_t)((KT) + 8) * QKV3, lk_ + 512);         \
        GLDS16(gv + (KT),                      lv_);               \
        GLDS16(gv + (KT) + 8 * SEQ,            lv_ + 512);         \
    } while (0)

    float m[2] = {-1e30f, -1e30f}, l[2] = {0.0f, 0.0f};
    f32x4 o[2][4] = {};

    STAGE(0, 0);
    int cur = 0;
    for (int kt = 0; kt < SEQ; kt += 64) {
        __syncthreads();   // drains vmcnt(0): STAGE(kt) resident; buf cur^1 free
        if (kt + 64 < SEQ) STAGE(cur ^ 1, kt + 64);   // fire-and-forget

        #pragma unroll
        for (int mf = 0; mf < 2; ++mf) {
            // S^T = K Q^T : sv[kf][r] = S[kv=kf*16+hi*4+r][q]
            f32x4 sv[4];
            __builtin_amdgcn_s_setprio(1);
            #pragma unroll
            for (int kf = 0; kf < 4; ++kf) {
                f32x4 z = {0.f, 0.f, 0.f, 0.f};
                sv[kf] = z;
                #pragma unroll
                for (int ks = 0; ks < 2; ++ks) {
                    const int row = kf * 16 + q;
                    const int bo = (row * 128 + ks * 64 + (hi << 4)) ^ ((row & 7) << 4);
                    const bf16x8 kfrag = *(const bf16x8*)((const char*)&Ks[cur][0] + bo);
                    sv[kf] = mfma16(kfrag, qf[mf][ks], sv[kf]);
                }
            }
            __builtin_amdgcn_s_setprio(0);

            // in-register row max (16 values) + 2 shfl across hi-groups
            float pmax;
            {
                float a = fmaxf(fmaxf(sv[0][0], sv[0][1]), fmaxf(sv[0][2], sv[0][3]));
                float b2 = fmaxf(fmaxf(sv[1][0], sv[1][1]), fmaxf(sv[1][2], sv[1][3]));
                float c = fmaxf(fmaxf(sv[2][0], sv[2][1]), fmaxf(sv[2][2], sv[2][3]));
                float d = fmaxf(fmaxf(sv[3][0], sv[3][1]), fmaxf(sv[3][2], sv[3][3]));
                pmax = fmaxf(fmaxf(a, b2), fmaxf(c, d));
            }
            pmax = fmaxf(pmax, __shfl_xor(pmax, 16, 64));
            pmax = fmaxf(pmax, __shfl_xor(pmax, 32, 64));

            // defer-max (THR=8): rescale only when max grew materially
            if (__any(pmax - m[mf] > 8.0f)) {
                const float nm = fmaxf(m[mf], pmax);
                const float fr = __expf(m[mf] - nm);
                l[mf] *= fr;
                #pragma unroll
                for (int df = 0; df < 4; ++df) {
                    o[mf][df][0] *= fr; o[mf][df][1] *= fr;
                    o[mf][df][2] *= fr; o[mf][df][3] *= fr;
                }
                m[mf] = nm;
            }

            // P = exp(S - m): pack 4 bf16 -> one b64 write per kf
            float rsum = 0.0f;
            #pragma unroll
            for (int kf = 0; kf < 4; ++kf) {
                float p0 = __expf(sv[kf][0] - m[mf]);
                float p1 = __expf(sv[kf][1] - m[mf]);
                float p2 = __expf(sv[kf][2] - m[mf]);
                float p3 = __expf(sv[kf][3] - m[mf]);
                rsum += (p0 + p1) + (p2 + p3);
                bf16x4 pk = { (bf16)p0, (bf16)p1, (bf16)p2, (bf16)p3 };
                const int bo = (q * 128 + kf * 32 + hi * 8) ^ ((q & 7) << 4);
                *(bf16x4*)((char*)Ps[wave] + bo) = pk;
            }
            rsum += __shfl_xor(rsum, 16, 64);
            rsum += __shfl_xor(rsum, 32, 64);
            l[mf] += rsum;

            // P B-fragments: col q, kv-slots ks*32 + hi*8 + j
            bf16x8 pf[2];
            #pragma unroll
            for (int ks = 0; ks < 2; ++ks) {
                const int bo = (q * 128 + ks * 64 + (hi << 4)) ^ ((q & 7) << 4);
                pf[ks] = *(const bf16x8*)((const char*)Ps[wave] + bo);
            }
            // O^T += V^T P^T : o[mf][df] has col q, rows d = df*16 + hi*4 + r
            __builtin_amdgcn_s_setprio(1);
            #pragma unroll
            for (int df = 0; df < 4; ++df)
                #pragma unroll
                for (int ks = 0; ks < 2; ++ks) {
                    const int rowv = df * 16 + q;
                    const int bo = (rowv * 128 + ks * 64 + (hi << 4)) ^ ((rowv & 7) << 4);
                    const bf16x8 vfrag = *(const bf16x8*)((const char*)&Vs[cur][0] + bo);
                    o[mf][df] = mfma16(vfrag, pf[ks], o[mf][df]);
                }
            __builtin_amdgcn_s_setprio(0);
        }
        cur ^= 1;
    }
#undef STAGE

    // epilogue: normalize, pack 4 bf16 (consecutive d) per 8B store
    #pragma unroll
    for (int mf = 0; mf < 2; ++mf) {
        const float inv = 1.0f / l[mf];
        const int grow = b * SEQ + q0 + mf * 16 + q;
        #pragma unroll
        for (int df = 0; df < 4; ++df) {
            bf16x4 pk = { (bf16)(o[mf][df][0] * inv), (bf16)(o[mf][df][1] * inv),
                          (bf16)(o[mf][df][2] * inv), (bf16)(o[mf][df][3] * inv) };
            *(bf16x4*)(out + (size_t)grow * DIMM + h * DHEAD + df * 16 + hi * 4) = pk;
        }
    }
}

// ---------------------------------------------------------------------------
extern "C" void kernel_launch(void* const* d_in, const int* in_sizes, int n_in,
                              void* d_out, int out_size, void* d_ws, size_t ws_size,
                              hipStream_t stream)
{
    (void)in_sizes; (void)n_in; (void)out_size; (void)ws_size;
    const float* x    = (const float*)d_in[0];
    const float* ln1g = (const float*)d_in[1];
    const float* ln1b = (const float*)d_in[2];
    const float* ln2g = (const float*)d_in[3];
    const float* ln2b = (const float*)d_in[4];
    const float* wqkv = (const float*)d_in[5];
    const float* wout = (const float*)d_in[6];
    const float* bout = (const float*)d_in[7];
    const float* wff1 = (const float*)d_in[8];
    const float* bff1 = (const float*)d_in[9];
    const float* wff2 = (const float*)d_in[10];
    const float* bff2 = (const float*)d_in[11];

    char* ws = (char*)d_ws;
    bf16*  wqkvT = (bf16*)(ws);                           // [3072][1024]      6.0 MB
    bf16*  woutT = (bf16*)(ws + 6291456);                 // [1024][1024]      2.0 MB
    bf16*  wff1T = (bf16*)(ws + 8388608);                 // [4096][1024]      8.0 MB
    bf16*  wff2T = (bf16*)(ws + 16777216);                // [1024][4096]      8.0 MB
    float* x2    = (float*)(ws + 25165824);               // [4096][1024] fp32 (after attn)
    bf16*  vT    = (bf16*)(ws + 25165824);                // [32][64][2048]    8 MB (attn phase only)
    bf16*  hbuf  = (bf16*)(ws + 41943040);                // [4096][1024]
    bf16*  qkvb  = (bf16*)(ws + 50331648);                // [4096][3072]
    bf16*  attnb = (bf16*)(ws + 75497472);                // [4096][1024]
    bf16*  fbuf  = (bf16*)(ws + 50331648);                // [4096][4096]

    const dim3 blk(256);
    tcast_kernel<<<dim3(QKV3 / 32, DIMM / 32), blk, 0, stream>>>(wqkv, wqkvT, DIMM, QKV3);
    tcast_kernel<<<dim3(DIMM / 32, DIMM / 32), blk, 0, stream>>>(wout, woutT, DIMM, DIMM);
    tcast_kernel<<<dim3(FFD  / 32, DIMM / 32), blk, 0, stream>>>(wff1, wff1T, DIMM, FFD);
    tcast_kernel<<<dim3(DIMM / 32, FFD  / 32), blk, 0, stream>>>(wff2, wff2T, FFD, DIMM);

    ln_cast_kernel<<<NROWS, blk, 0, stream>>>(x, ln1g, ln1b, hbuf);
    gemm_bt_kernel<0><<<(NROWS / 128) * (QKV3 / 128), blk, 0, stream>>>(
        hbuf, wqkvT, nullptr, nullptr, qkvb, NROWS, QKV3, DIMM);
    vtrans_kernel<<<dim3(SEQ / 64, BATCH * NHEAD), blk, 0, stream>>>(qkvb, vT);
    attn_kernel<<<dim3(512), blk, 0, stream>>>(qkvb, vT, attnb);
    gemm_bt_kernel<1><<<(NROWS / 128) * (DIMM / 128), blk, 0, stream>>>(
        attnb, woutT, bout, x, x2, NROWS, DIMM, DIMM);
    ln_cast_kernel<<<NROWS, blk, 0, stream>>>(x2, ln2g, ln2b, hbuf);
    gemm_bt_kernel<2><<<(NROWS / 128) * (FFD / 128), blk, 0, stream>>>(
        hbuf, wff1T, bff1, nullptr, fbuf, NROWS, FFD, DIMM);
    gemm_bt_kernel<1><<<(NROWS / 128) * (DIMM / 128), blk, 0, stream>>>(
        fbuf, wff2T, bff2, x2, (float*)d_out, NROWS, DIMM, FFD);
}

// Round 6
// 279.872 us; speedup vs baseline: 1.4134x; 1.1129x over previous
//
#include <hip/hip_runtime.h>
#include <hip/hip_bf16.h>
#include <math.h>

#define SEQ   2048
#define BATCH 2
#define NROWS 4096      /* BATCH*SEQ */
#define DIMM  1024
#define QKV3  3072
#define FFD   4096
#define NHEAD 16
#define DHEAD 64

typedef __bf16 bf16;
typedef __bf16 bf16x4 __attribute__((ext_vector_type(4)));
typedef __bf16 bf16x8 __attribute__((ext_vector_type(8)));
typedef float  f32x4  __attribute__((ext_vector_type(4)));

static __device__ __forceinline__ f32x4 mfma16(bf16x8 a, bf16x8 b, f32x4 c) {
    return __builtin_amdgcn_mfma_f32_16x16x32_bf16(a, b, c, 0, 0, 0);
}

#define GLDS16(gp, lp) __builtin_amdgcn_global_load_lds( \
    (__attribute__((address_space(1))) void*)(gp),       \
    (__attribute__((address_space(3))) void*)(lp), 16, 0, 0)

// ---------------------------------------------------------------------------
// Transpose + cast: src fp32 [K][N] -> dst bf16 [N][K]
// ---------------------------------------------------------------------------
__global__ __launch_bounds__(256) void tcast_kernel(
    const float* __restrict__ src, bf16* __restrict__ dst, int K, int N)
{
    __shared__ float tile[32][33];
    const int n0 = blockIdx.x * 32;
    const int k0 = blockIdx.y * 32;
    const int r = threadIdx.x >> 5;   // 0..7
    const int c = threadIdx.x & 31;
    #pragma unroll
    for (int i = 0; i < 4; ++i)
        tile[r + 8 * i][c] = src[(size_t)(k0 + r + 8 * i) * N + n0 + c];
    __syncthreads();
    #pragma unroll
    for (int i = 0; i < 4; ++i)
        dst[(size_t)(n0 + r + 8 * i) * K + k0 + c] = (bf16)tile[c][r + 8 * i];
}

// ---------------------------------------------------------------------------
// LayerNorm fp32 [NROWS][1024] -> bf16, one block per row
// ---------------------------------------------------------------------------
__global__ __launch_bounds__(256) void ln_cast_kernel(
    const float* __restrict__ x, const float* __restrict__ g,
    const float* __restrict__ b, bf16* __restrict__ out)
{
    const int row = blockIdx.x;
    const int t = threadIdx.x;
    const float4 v = ((const float4*)(x + (size_t)row * DIMM))[t];
    float s  = v.x + v.y + v.z + v.w;
    float sq = v.x * v.x + v.y * v.y + v.z * v.z + v.w * v.w;
    #pragma unroll
    for (int m = 1; m < 64; m <<= 1) {
        s  += __shfl_xor(s, m, 64);
        sq += __shfl_xor(sq, m, 64);
    }
    __shared__ float ss[4], ssq[4];
    const int wave = t >> 6;
    if ((t & 63) == 0) { ss[wave] = s; ssq[wave] = sq; }
    __syncthreads();
    s  = ss[0] + ss[1] + ss[2] + ss[3];
    sq = ssq[0] + ssq[1] + ssq[2] + ssq[3];
    const float mean = s * (1.0f / DIMM);
    const float var  = sq * (1.0f / DIMM) - mean * mean;
    const float rs   = rsqrtf(var + 1e-5f);
    const float4 gv = ((const float4*)g)[t];
    const float4 bv = ((const float4*)b)[t];
    bf16* o = out + (size_t)row * DIMM + t * 4;
    o[0] = (bf16)((v.x - mean) * rs * gv.x + bv.x);
    o[1] = (bf16)((v.y - mean) * rs * gv.y + bv.y);
    o[2] = (bf16)((v.z - mean) * rs * gv.z + bv.z);
    o[3] = (bf16)((v.w - mean) * rs * gv.w + bv.w);
}

// ---------------------------------------------------------------------------
// bf16 MFMA GEMM (m97 structure): C[M][N] = A[M][K] @ B[K][N], B given as
// BT[N][K], row stride ld. 128x128 tile, BK=32, 4 waves, 4x4 16x16x32 frags.
// XCD-chunk swizzle (T1): gridDim.x % 8 == 0 required.
// EPI: 0 = bf16 out; 1 = +bias +residual, fp32 out; 2 = +bias, GELU, bf16 out
//      3 = split-K partial: ks = idx / tiles; fp32 partial to (ks==0 ? Cout
//          : res-as-C2); A/BT advanced by ks*K columns.
// ---------------------------------------------------------------------------
template<int EPI>
__global__ __launch_bounds__(256, 2)
void gemm_bt_kernel(const bf16* __restrict__ A, const bf16* __restrict__ BT,
                    const float* __restrict__ bias, const float* __restrict__ res,
                    void* __restrict__ Cout, int M, int N, int K, int ld)
{
    __shared__ bf16 As[4096];   // [128 m][32 k]
    __shared__ bf16 Bs[4096];   // [128 n][32 k]
    const int nb = N >> 7;
    const int chunk = (int)gridDim.x >> 3;
    int idx = (blockIdx.x & 7) * chunk + (blockIdx.x >> 3);
    int ks = 0;
    if (EPI == 3) {
        const int tiles = (M >> 7) * nb;
        ks = idx / tiles;
        idx -= ks * tiles;
    }
    const int bm = idx / nb, bn = idx - bm * nb;
    const int tm = bm << 7, tn = bn << 7;
    const int tid = threadIdx.x;
    const int lane = tid & 63, wave = tid >> 6;
    const int wm = (wave >> 1) << 6, wn = (wave & 1) << 6;
    const int kofs = ks * K;   // column offset for split-K slice

    const bf16* ga = A  + (size_t)(tm + wave * 32 + (lane >> 2)) * ld + kofs + ((lane & 3) << 3);
    const bf16* gb = BT + (size_t)(tn + wave * 32 + (lane >> 2)) * ld + kofs + ((lane & 3) << 3);
    bf16* la = As + wave * 1024;
    bf16* lb = Bs + wave * 1024;
    const size_t k16 = (size_t)16 * ld;

    f32x4 acc[4][4] = {};
    const int ro = (lane & 15) * 32 + ((lane >> 4) << 3);

    for (int k0 = 0; k0 < K; k0 += 32) {
        __syncthreads();
        GLDS16(ga + k0,       la);
        GLDS16(ga + k0 + k16, la + 512);
        GLDS16(gb + k0,       lb);
        GLDS16(gb + k0 + k16, lb + 512);
        __syncthreads();
        bf16x8 af[4], bfr[4];
        #pragma unroll
        for (int i = 0; i < 4; ++i) {
            af[i]  = *(const bf16x8*)(As + (wm + i * 16) * 32 + ro);
            bfr[i] = *(const bf16x8*)(Bs + (wn + i * 16) * 32 + ro);
        }
        #pragma unroll
        for (int i = 0; i < 4; ++i)
            #pragma unroll
            for (int j = 0; j < 4; ++j)
                acc[i][j] = mfma16(af[i], bfr[j], acc[i][j]);
    }

    const int r0 = tm + wm + ((lane >> 4) << 2);
    const int c0 = tn + wn + (lane & 15);
    if (EPI == 0) {
        bf16* C = (bf16*)Cout;
        #pragma unroll
        for (int i = 0; i < 4; ++i)
            #pragma unroll
            for (int j = 0; j < 4; ++j)
                #pragma unroll
                for (int r = 0; r < 4; ++r)
                    C[(size_t)(r0 + i * 16 + r) * N + (c0 + j * 16)] = (bf16)acc[i][j][r];
    } else if (EPI == 1) {
        float* C = (float*)Cout;
        #pragma unroll
        for (int j = 0; j < 4; ++j) {
            const float bv = bias[c0 + j * 16];
            #pragma unroll
            for (int i = 0; i < 4; ++i)
                #pragma unroll
                for (int r = 0; r < 4; ++r) {
                    const size_t idx2 = (size_t)(r0 + i * 16 + r) * N + (c0 + j * 16);
                    C[idx2] = acc[i][j][r] + bv + res[idx2];
                }
        }
    } else if (EPI == 2) {
        bf16* C = (bf16*)Cout;
        #pragma unroll
        for (int j = 0; j < 4; ++j) {
            const float bv = bias[c0 + j * 16];
            #pragma unroll
            for (int i = 0; i < 4; ++i)
                #pragma unroll
                for (int r = 0; r < 4; ++r) {
                    const float v = acc[i][j][r] + bv;
                    const float gl = 0.5f * v * (1.0f + erff(v * 0.70710678118654752f));
                    C[(size_t)(r0 + i * 16 + r) * N + (c0 + j * 16)] = (bf16)gl;
                }
        }
    } else {   // EPI == 3: fp32 partial, slice ks
        float* C = (float*)(ks == 0 ? Cout : (void*)res);
        #pragma unroll
        for (int j = 0; j < 4; ++j)
            #pragma unroll
            for (int i = 0; i < 4; ++i)
                #pragma unroll
                for (int r = 0; r < 4; ++r)
                    C[(size_t)(r0 + i * 16 + r) * N + (c0 + j * 16)] = acc[i][j][r];
    }
}

// ---------------------------------------------------------------------------
// FF2 split-K reduce: out = p0 + p1 + bias + res  (all fp32, [NROWS][DIMM])
// ---------------------------------------------------------------------------
__global__ __launch_bounds__(256) void ff2_reduce_kernel(
    const float* __restrict__ p0, const float* __restrict__ p1,
    const float* __restrict__ bias, const float* __restrict__ res,
    float* __restrict__ out)
{
    const int i = blockIdx.x * 256 + threadIdx.x;    // float4 index
    const float4 a = ((const float4*)p0)[i];
    const float4 b = ((const float4*)p1)[i];
    const float4 r = ((const float4*)res)[i];
    const float4 g = ((const float4*)bias)[i & 255]; // DIMM/4 = 256 float4/row
    float4 o;
    o.x = a.x + b.x + r.x + g.x;
    o.y = a.y + b.y + r.y + g.y;
    o.z = a.z + b.z + r.z + g.z;
    o.w = a.w + b.w + r.w + g.w;
    ((float4*)out)[i] = o;
}

// ---------------------------------------------------------------------------
// V transpose per head: qkv[b][n][2*DIMM + h*64 + d] -> vT[bh][d][n]
// ---------------------------------------------------------------------------
__global__ __launch_bounds__(256) void vtrans_kernel(
    const bf16* __restrict__ qkv, bf16* __restrict__ vT)
{
    __shared__ bf16 t[64 * 64];
    const int n0 = blockIdx.x * 64;
    const int bh = blockIdx.y;
    const int b = bh >> 4, h = bh & 15;
    const bf16* src = qkv + (size_t)(b * SEQ + n0) * QKV3 + 2 * DIMM + h * DHEAD;

    #pragma unroll
    for (int it = 0; it < 2; ++it) {
        const int c = it * 256 + threadIdx.x;   // 512 chunks of 8 elems
        const int n = c >> 3, d8 = (c & 7) * 8;
        const bf16x8 v8 = *(const bf16x8*)(src + (size_t)n * QKV3 + d8);
        const int byte = (n * 128 + d8 * 2) ^ (((n >> 3) & 7) << 4);
        *(bf16x8*)((char*)t + byte) = v8;
    }
    __syncthreads();
    #pragma unroll
    for (int it = 0; it < 2; ++it) {
        const int c = it * 256 + threadIdx.x;
        const int d = c >> 3, nc = c & 7;
        bf16x8 o8;
        #pragma unroll
        for (int i = 0; i < 8; ++i) {
            const int n = nc * 8 + i;
            const int byte = (n * 128 + d * 2) ^ ((nc & 7) << 4);
            o8[i] = *(const bf16*)((const char*)t + byte);
        }
        *(bf16x8*)(vT + (size_t)bh * DHEAD * SEQ + (size_t)d * SEQ + n0 + nc * 8) = o8;
    }
}

// ---------------------------------------------------------------------------
// Flash attention v4 (swapped-operand, r4 structure — unchanged).
// ---------------------------------------------------------------------------
__global__ __launch_bounds__(256, 2)
void attn_kernel(const bf16* __restrict__ qkv, const bf16* __restrict__ vT,
                 bf16* __restrict__ out)
{
    __shared__ bf16 Ks[2][64 * 64];
    __shared__ bf16 Vs[2][64 * 64];
    __shared__ bf16 Ps[4][32 * 64];
    const int bid = blockIdx.x;                   // 0..511
    const int idx = (bid & 7) * 64 + (bid >> 3);  // bijective XCD swizzle
    const int qt = idx & 15;
    const int bh = idx >> 4;
    const int b = bh >> 4, h = bh & 15;
    const int tid = threadIdx.x;
    const int lane = tid & 63, wave = tid >> 6;
    const int q = lane & 15, hi = lane >> 4;

    const bf16* qbase = qkv + (size_t)(b * SEQ) * QKV3 + h * DHEAD;
    const bf16* kbase = qbase + DIMM;
    const bf16* vbase = vT + (size_t)bh * DHEAD * SEQ;

    const int q0 = qt * 128 + wave * 32;
    bf16x8 qf[2][2];
    #pragma unroll
    for (int mf = 0; mf < 2; ++mf) {
        const bf16* qp = qbase + (size_t)(q0 + mf * 16 + q) * QKV3 + (hi << 3);
        qf[mf][0] = *(const bf16x8*)qp;
        qf[mf][1] = *(const bf16x8*)(qp + 32);
        #pragma unroll
        for (int j = 0; j < 8; ++j) {
            qf[mf][0][j] = (bf16)((float)qf[mf][0][j] * 0.125f);
            qf[mf][1][j] = (bf16)((float)qf[mf][1][j] * 0.125f);
        }
    }

    const int srow = lane >> 3;
    const int scol = ((lane & 7) ^ srow) << 3;
    const bf16* gk = kbase + (size_t)(wave * 16 + srow) * QKV3 + scol;
    const bf16* gv = vbase + (size_t)(wave * 16 + srow) * SEQ + scol;

#define STAGE(BUF, KT) do {                                        \
        bf16* lk_ = &Ks[BUF][wave * 1024];                         \
        bf16* lv_ = &Vs[BUF][wave * 1024];                         \
        GLDS16(gk + (size_t)(KT) * QKV3,       lk_);               \
        GLDS16(gk + (size_t)((KT) + 8) * QKV3, lk_ + 512);         \
        GLDS16(gv + (KT),                      lv_);               \
        GLDS16(gv + (KT) + 8 * SEQ,            lv_ + 512);         \
    } while (0)

    float m[2] = {-1e30f, -1e30f}, l[2] = {0.0f, 0.0f};
    f32x4 o[2][4] = {};

    STAGE(0, 0);
    int cur = 0;
    for (int kt = 0; kt < SEQ; kt += 64) {
        __syncthreads();
        if (kt + 64 < SEQ) STAGE(cur ^ 1, kt + 64);

        #pragma unroll
        for (int mf = 0; mf < 2; ++mf) {
            f32x4 sv[4];
            __builtin_amdgcn_s_setprio(1);
            #pragma unroll
            for (int kf = 0; kf < 4; ++kf) {
                f32x4 z = {0.f, 0.f, 0.f, 0.f};
                sv[kf] = z;
                #pragma unroll
                for (int ks = 0; ks < 2; ++ks) {
                    const int row = kf * 16 + q;
                    const int bo = (row * 128 + ks * 64 + (hi << 4)) ^ ((row & 7) << 4);
                    const bf16x8 kfrag = *(const bf16x8*)((const char*)&Ks[cur][0] + bo);
                    sv[kf] = mfma16(kfrag, qf[mf][ks], sv[kf]);
                }
            }
            __builtin_amdgcn_s_setprio(0);

            float pmax;
            {
                float a = fmaxf(fmaxf(sv[0][0], sv[0][1]), fmaxf(sv[0][2], sv[0][3]));
                float b2 = fmaxf(fmaxf(sv[1][0], sv[1][1]), fmaxf(sv[1][2], sv[1][3]));
                float c = fmaxf(fmaxf(sv[2][0], sv[2][1]), fmaxf(sv[2][2], sv[2][3]));
                float d = fmaxf(fmaxf(sv[3][0], sv[3][1]), fmaxf(sv[3][2], sv[3][3]));
                pmax = fmaxf(fmaxf(a, b2), fmaxf(c, d));
            }
            pmax = fmaxf(pmax, __shfl_xor(pmax, 16, 64));
            pmax = fmaxf(pmax, __shfl_xor(pmax, 32, 64));

            if (__any(pmax - m[mf] > 8.0f)) {
                const float nm = fmaxf(m[mf], pmax);
                const float fr = __expf(m[mf] - nm);
                l[mf] *= fr;
                #pragma unroll
                for (int df = 0; df < 4; ++df) {
                    o[mf][df][0] *= fr; o[mf][df][1] *= fr;
                    o[mf][df][2] *= fr; o[mf][df][3] *= fr;
                }
                m[mf] = nm;
            }

            float rsum = 0.0f;
            #pragma unroll
            for (int kf = 0; kf < 4; ++kf) {
                float p0 = __expf(sv[kf][0] - m[mf]);
                float p1 = __expf(sv[kf][1] - m[mf]);
                float p2 = __expf(sv[kf][2] - m[mf]);
                float p3 = __expf(sv[kf][3] - m[mf]);
                rsum += (p0 + p1) + (p2 + p3);
                bf16x4 pk = { (bf16)p0, (bf16)p1, (bf16)p2, (bf16)p3 };
                const int bo = (q * 128 + kf * 32 + hi * 8) ^ ((q & 7) << 4);
                *(bf16x4*)((char*)Ps[wave] + bo) = pk;
            }
            rsum += __shfl_xor(rsum, 16, 64);
            rsum += __shfl_xor(rsum, 32, 64);
            l[mf] += rsum;

            bf16x8 pf[2];
            #pragma unroll
            for (int ks = 0; ks < 2; ++ks) {
                const int bo = (q * 128 + ks * 64 + (hi << 4)) ^ ((q & 7) << 4);
                pf[ks] = *(const bf16x8*)((const char*)Ps[wave] + bo);
            }
            __builtin_amdgcn_s_setprio(1);
            #pragma unroll
            for (int df = 0; df < 4; ++df)
                #pragma unroll
                for (int ks = 0; ks < 2; ++ks) {
                    const int rowv = df * 16 + q;
                    const int bo = (rowv * 128 + ks * 64 + (hi << 4)) ^ ((rowv & 7) << 4);
                    const bf16x8 vfrag = *(const bf16x8*)((const char*)&Vs[cur][0] + bo);
                    o[mf][df] = mfma16(vfrag, pf[ks], o[mf][df]);
                }
            __builtin_amdgcn_s_setprio(0);
        }
        cur ^= 1;
    }
#undef STAGE

    #pragma unroll
    for (int mf = 0; mf < 2; ++mf) {
        const float inv = 1.0f / l[mf];
        const int grow = b * SEQ + q0 + mf * 16 + q;
        #pragma unroll
        for (int df = 0; df < 4; ++df) {
            bf16x4 pk = { (bf16)(o[mf][df][0] * inv), (bf16)(o[mf][df][1] * inv),
                          (bf16)(o[mf][df][2] * inv), (bf16)(o[mf][df][3] * inv) };
            *(bf16x4*)(out + (size_t)grow * DIMM + h * DHEAD + df * 16 + hi * 4) = pk;
        }
    }
}

// ---------------------------------------------------------------------------
extern "C" void kernel_launch(void* const* d_in, const int* in_sizes, int n_in,
                              void* d_out, int out_size, void* d_ws, size_t ws_size,
                              hipStream_t stream)
{
    (void)in_sizes; (void)n_in; (void)out_size;
    const float* x    = (const float*)d_in[0];
    const float* ln1g = (const float*)d_in[1];
    const float* ln1b = (const float*)d_in[2];
    const float* ln2g = (const float*)d_in[3];
    const float* ln2b = (const float*)d_in[4];
    const float* wqkv = (const float*)d_in[5];
    const float* wout = (const float*)d_in[6];
    const float* bout = (const float*)d_in[7];
    const float* wff1 = (const float*)d_in[8];
    const float* bff1 = (const float*)d_in[9];
    const float* wff2 = (const float*)d_in[10];
    const float* bff2 = (const float*)d_in[11];

    char* ws = (char*)d_ws;
    const dim3 blk(256);
    const bool splitk = ws_size >= 92274688ULL;   // 88 MB packed layout

    if (splitk) {
        // Phase-lifetime-packed layout (all live ranges disjoint; 88 MB):
        //   wff2T  0..8M      (live -> FF2)
        //   woutT  8..10M     (live -> out-proj)
        //   wff1T  10..18M    (live -> FF1)
        //   wqkvT  18..24M    (live -> QKV gemm)
        //   hbuf   24..32M    (LN1 -> QKV; reused LN2 -> FF1)
        //   qkvb   32..56M    (QKV -> attn)
        //   vT     56..64M    (vtrans -> attn)
        //   attnb  64..72M    (attn -> out-proj)
        //   x2     72..88M    (out-proj -> reduce)
        //   fbuf   40..72M    (FF1 -> FF2; over dead qkvb-tail/vT/attnb)
        //   p0     8..24M     (FF2 -> reduce; over dead woutT/wff1T/wqkvT)
        //   p1     24..40M    (FF2 -> reduce; over dead hbuf/qkvb-head)
        bf16*  wff2T = (bf16*)(ws);
        bf16*  woutT = (bf16*)(ws + 8388608);
        bf16*  wff1T = (bf16*)(ws + 10485760);
        bf16*  wqkvT = (bf16*)(ws + 18874368);
        bf16*  hbuf  = (bf16*)(ws + 25165824);
        bf16*  qkvb  = (bf16*)(ws + 33554432);
        bf16*  vT    = (bf16*)(ws + 58720256);
        bf16*  attnb = (bf16*)(ws + 67108864);
        float* x2    = (float*)(ws + 75497472);
        bf16*  fbuf  = (bf16*)(ws + 41943040);
        float* p0    = (float*)(ws + 8388608);
        float* p1    = (float*)(ws + 25165824);

        tcast_kernel<<<dim3(QKV3 / 32, DIMM / 32), blk, 0, stream>>>(wqkv, wqkvT, DIMM, QKV3);
        tcast_kernel<<<dim3(DIMM / 32, DIMM / 32), blk, 0, stream>>>(wout, woutT, DIMM, DIMM);
        tcast_kernel<<<dim3(FFD  / 32, DIMM / 32), blk, 0, stream>>>(wff1, wff1T, DIMM, FFD);
        tcast_kernel<<<dim3(DIMM / 32, FFD  / 32), blk, 0, stream>>>(wff2, wff2T, FFD, DIMM);

        ln_cast_kernel<<<NROWS, blk, 0, stream>>>(x, ln1g, ln1b, hbuf);
        gemm_bt_kernel<0><<<(NROWS / 128) * (QKV3 / 128), blk, 0, stream>>>(
            hbuf, wqkvT, nullptr, nullptr, qkvb, NROWS, QKV3, DIMM, DIMM);
        vtrans_kernel<<<dim3(SEQ / 64, BATCH * NHEAD), blk, 0, stream>>>(qkvb, vT);
        attn_kernel<<<dim3(512), blk, 0, stream>>>(qkvb, vT, attnb);
        gemm_bt_kernel<1><<<(NROWS / 128) * (DIMM / 128), blk, 0, stream>>>(
            attnb, woutT, bout, x, x2, NROWS, DIMM, DIMM, DIMM);
        ln_cast_kernel<<<NROWS, blk, 0, stream>>>(x2, ln2g, ln2b, hbuf);
        gemm_bt_kernel<2><<<(NROWS / 128) * (FFD / 128), blk, 0, stream>>>(
            hbuf, wff1T, bff1, nullptr, fbuf, NROWS, FFD, DIMM, DIMM);
        // FF2 split-K=2: 512 blocks (2/CU); slices K=2048; then fused reduce.
        gemm_bt_kernel<3><<<2 * (NROWS / 128) * (DIMM / 128), blk, 0, stream>>>(
            fbuf, wff2T, nullptr, (const float*)p1, p0, NROWS, DIMM, FFD / 2, FFD);
        ff2_reduce_kernel<<<(NROWS * DIMM) / 1024, blk, 0, stream>>>(
            p0, p1, bff2, x2, (float*)d_out);
    } else {
        // Fallback: round-4 proven layout, single-pass FF2.
        bf16*  wqkvT = (bf16*)(ws);
        bf16*  woutT = (bf16*)(ws + 6291456);
        bf16*  wff1T = (bf16*)(ws + 8388608);
        bf16*  wff2T = (bf16*)(ws + 16777216);
        float* x2    = (float*)(ws + 25165824);
        bf16*  vT    = (bf16*)(ws + 25165824);
        bf16*  hbuf  = (bf16*)(ws + 41943040);
        bf16*  qkvb  = (bf16*)(ws + 50331648);
        bf16*  attnb = (bf16*)(ws + 75497472);
        bf16*  fbuf  = (bf16*)(ws + 50331648);

        tcast_kernel<<<dim3(QKV3 / 32, DIMM / 32), blk, 0, stream>>>(wqkv, wqkvT, DIMM, QKV3);
        tcast_kernel<<<dim3(DIMM / 32, DIMM / 32), blk, 0, stream>>>(wout, woutT, DIMM, DIMM);
        tcast_kernel<<<dim3(FFD  / 32, DIMM / 32), blk, 0, stream>>>(wff1, wff1T, DIMM, FFD);
        tcast_kernel<<<dim3(DIMM / 32, FFD  / 32), blk, 0, stream>>>(wff2, wff2T, FFD, DIMM);

        ln_cast_kernel<<<NROWS, blk, 0, stream>>>(x, ln1g, ln1b, hbuf);
        gemm_bt_kernel<0><<<(NROWS / 128) * (QKV3 / 128), blk, 0, stream>>>(
            hbuf, wqkvT, nullptr, nullptr, qkvb, NROWS, QKV3, DIMM, DIMM);
        vtrans_kernel<<<dim3(SEQ / 64, BATCH * NHEAD), blk, 0, stream>>>(qkvb, vT);
        attn_kernel<<<dim3(512), blk, 0, stream>>>(qkvb, vT, attnb);
        gemm_bt_kernel<1><<<(NROWS / 128) * (DIMM / 128), blk, 0, stream>>>(
            attnb, woutT, bout, x, x2, NROWS, DIMM, DIMM, DIMM);
        ln_cast_kernel<<<NROWS, blk, 0, stream>>>(x2, ln2g, ln2b, hbuf);
        gemm_bt_kernel<2><<<(NROWS / 128) * (FFD / 128), blk, 0, stream>>>(
            hbuf, wff1T, bff1, nullptr, fbuf, NROWS, FFD, DIMM, DIMM);
        gemm_bt_kernel<1><<<(NROWS / 128) * (DIMM / 128), blk, 0, stream>>>(
            fbuf, wff2T, bff2, x2, (float*)d_out, NROWS, DIMM, FFD, FFD);
    }
}

// Round 7
// 274.468 us; speedup vs baseline: 1.4412x; 1.0197x over previous
//
#include <hip/hip_runtime.h>
#include <hip/hip_bf16.h>
#include <math.h>

#define SEQ   2048
#define BATCH 2
#define NROWS 4096      /* BATCH*SEQ */
#define DIMM  1024
#define QKV3  3072
#define FFD   4096
#define NHEAD 16
#define DHEAD 64

typedef __bf16 bf16;
typedef __bf16 bf16x4 __attribute__((ext_vector_type(4)));
typedef __bf16 bf16x8 __attribute__((ext_vector_type(8)));
typedef float  f32x4  __attribute__((ext_vector_type(4)));

static __device__ __forceinline__ f32x4 mfma16(bf16x8 a, bf16x8 b, f32x4 c) {
    return __builtin_amdgcn_mfma_f32_16x16x32_bf16(a, b, c, 0, 0, 0);
}

#define GLDS16(gp, lp) __builtin_amdgcn_global_load_lds( \
    (__attribute__((address_space(1))) void*)(gp),       \
    (__attribute__((address_space(3))) void*)(lp), 16, 0, 0)

// ---------------------------------------------------------------------------
// Transpose + cast: src fp32 [K][N] -> dst bf16 [N][K]
// ---------------------------------------------------------------------------
__global__ __launch_bounds__(256) void tcast_kernel(
    const float* __restrict__ src, bf16* __restrict__ dst, int K, int N)
{
    __shared__ float tile[32][33];
    const int n0 = blockIdx.x * 32;
    const int k0 = blockIdx.y * 32;
    const int r = threadIdx.x >> 5;   // 0..7
    const int c = threadIdx.x & 31;
    #pragma unroll
    for (int i = 0; i < 4; ++i)
        tile[r + 8 * i][c] = src[(size_t)(k0 + r + 8 * i) * N + n0 + c];
    __syncthreads();
    #pragma unroll
    for (int i = 0; i < 4; ++i)
        dst[(size_t)(n0 + r + 8 * i) * K + k0 + c] = (bf16)tile[c][r + 8 * i];
}

// ---------------------------------------------------------------------------
// LayerNorm fp32 [NROWS][1024] -> bf16, one block per row
// ---------------------------------------------------------------------------
__global__ __launch_bounds__(256) void ln_cast_kernel(
    const float* __restrict__ x, const float* __restrict__ g,
    const float* __restrict__ b, bf16* __restrict__ out)
{
    const int row = blockIdx.x;
    const int t = threadIdx.x;
    const float4 v = ((const float4*)(x + (size_t)row * DIMM))[t];
    float s  = v.x + v.y + v.z + v.w;
    float sq = v.x * v.x + v.y * v.y + v.z * v.z + v.w * v.w;
    #pragma unroll
    for (int m = 1; m < 64; m <<= 1) {
        s  += __shfl_xor(s, m, 64);
        sq += __shfl_xor(sq, m, 64);
    }
    __shared__ float ss[4], ssq[4];
    const int wave = t >> 6;
    if ((t & 63) == 0) { ss[wave] = s; ssq[wave] = sq; }
    __syncthreads();
    s  = ss[0] + ss[1] + ss[2] + ss[3];
    sq = ssq[0] + ssq[1] + ssq[2] + ssq[3];
    const float mean = s * (1.0f / DIMM);
    const float var  = sq * (1.0f / DIMM) - mean * mean;
    const float rs   = rsqrtf(var + 1e-5f);
    const float4 gv = ((const float4*)g)[t];
    const float4 bv = ((const float4*)b)[t];
    bf16* o = out + (size_t)row * DIMM + t * 4;
    o[0] = (bf16)((v.x - mean) * rs * gv.x + bv.x);
    o[1] = (bf16)((v.y - mean) * rs * gv.y + bv.y);
    o[2] = (bf16)((v.z - mean) * rs * gv.z + bv.z);
    o[3] = (bf16)((v.w - mean) * rs * gv.w + bv.w);
}

// ---------------------------------------------------------------------------
// bf16 MFMA GEMM (m97 structure): C[M][N] = A[M][K] @ B[K][N], B given as
// BT[N][K], row stride ld. 128x128 tile, BK=32, 4 waves, 4x4 16x16x32 frags.
// XCD-chunk swizzle (T1): gridDim.x % 8 == 0 required.
// EPI: 0 = bf16 out; 1 = +bias +residual, fp32 out; 2 = +bias, GELU, bf16 out
//      3 = split-K partial: ks = idx / tiles; fp32 partial to (ks==0 ? Cout
//          : res-as-C2); A/BT advanced by ks*K columns.
// ---------------------------------------------------------------------------
template<int EPI>
__global__ __launch_bounds__(256, 2)
void gemm_bt_kernel(const bf16* __restrict__ A, const bf16* __restrict__ BT,
                    const float* __restrict__ bias, const float* __restrict__ res,
                    void* __restrict__ Cout, int M, int N, int K, int ld)
{
    __shared__ bf16 As[4096];   // [128 m][32 k]
    __shared__ bf16 Bs[4096];   // [128 n][32 k]
    const int nb = N >> 7;
    const int chunk = (int)gridDim.x >> 3;
    int idx = (blockIdx.x & 7) * chunk + (blockIdx.x >> 3);
    int ks = 0;
    if (EPI == 3) {
        const int tiles = (M >> 7) * nb;
        ks = idx / tiles;
        idx -= ks * tiles;
    }
    const int bm = idx / nb, bn = idx - bm * nb;
    const int tm = bm << 7, tn = bn << 7;
    const int tid = threadIdx.x;
    const int lane = tid & 63, wave = tid >> 6;
    const int wm = (wave >> 1) << 6, wn = (wave & 1) << 6;
    const int kofs = ks * K;   // column offset for split-K slice

    const bf16* ga = A  + (size_t)(tm + wave * 32 + (lane >> 2)) * ld + kofs + ((lane & 3) << 3);
    const bf16* gb = BT + (size_t)(tn + wave * 32 + (lane >> 2)) * ld + kofs + ((lane & 3) << 3);
    bf16* la = As + wave * 1024;
    bf16* lb = Bs + wave * 1024;
    const size_t k16 = (size_t)16 * ld;

    f32x4 acc[4][4] = {};
    const int ro = (lane & 15) * 32 + ((lane >> 4) << 3);

    for (int k0 = 0; k0 < K; k0 += 32) {
        __syncthreads();
        GLDS16(ga + k0,       la);
        GLDS16(ga + k0 + k16, la + 512);
        GLDS16(gb + k0,       lb);
        GLDS16(gb + k0 + k16, lb + 512);
        __syncthreads();
        bf16x8 af[4], bfr[4];
        #pragma unroll
        for (int i = 0; i < 4; ++i) {
            af[i]  = *(const bf16x8*)(As + (wm + i * 16) * 32 + ro);
            bfr[i] = *(const bf16x8*)(Bs + (wn + i * 16) * 32 + ro);
        }
        #pragma unroll
        for (int i = 0; i < 4; ++i)
            #pragma unroll
            for (int j = 0; j < 4; ++j)
                acc[i][j] = mfma16(af[i], bfr[j], acc[i][j]);
    }

    const int r0 = tm + wm + ((lane >> 4) << 2);
    const int c0 = tn + wn + (lane & 15);
    if (EPI == 0) {
        bf16* C = (bf16*)Cout;
        #pragma unroll
        for (int i = 0; i < 4; ++i)
            #pragma unroll
            for (int j = 0; j < 4; ++j)
                #pragma unroll
                for (int r = 0; r < 4; ++r)
                    C[(size_t)(r0 + i * 16 + r) * N + (c0 + j * 16)] = (bf16)acc[i][j][r];
    } else if (EPI == 1) {
        float* C = (float*)Cout;
        #pragma unroll
        for (int j = 0; j < 4; ++j) {
            const float bv = bias[c0 + j * 16];
            #pragma unroll
            for (int i = 0; i < 4; ++i)
                #pragma unroll
                for (int r = 0; r < 4; ++r) {
                    const size_t idx2 = (size_t)(r0 + i * 16 + r) * N + (c0 + j * 16);
                    C[idx2] = acc[i][j][r] + bv + res[idx2];
                }
        }
    } else if (EPI == 2) {
        bf16* C = (bf16*)Cout;
        #pragma unroll
        for (int j = 0; j < 4; ++j) {
            const float bv = bias[c0 + j * 16];
            #pragma unroll
            for (int i = 0; i < 4; ++i)
                #pragma unroll
                for (int r = 0; r < 4; ++r) {
                    const float v = acc[i][j][r] + bv;
                    const float gl = 0.5f * v * (1.0f + erff(v * 0.70710678118654752f));
                    C[(size_t)(r0 + i * 16 + r) * N + (c0 + j * 16)] = (bf16)gl;
                }
        }
    } else {   // EPI == 3: fp32 partial, slice ks
        float* C = (float*)(ks == 0 ? Cout : (void*)res);
        #pragma unroll
        for (int j = 0; j < 4; ++j)
            #pragma unroll
            for (int i = 0; i < 4; ++i)
                #pragma unroll
                for (int r = 0; r < 4; ++r)
                    C[(size_t)(r0 + i * 16 + r) * N + (c0 + j * 16)] = acc[i][j][r];
    }
}

// ---------------------------------------------------------------------------
// FF2 split-K reduce: out = p0 + p1 + bias + res  (all fp32, [NROWS][DIMM])
// ---------------------------------------------------------------------------
__global__ __launch_bounds__(256) void ff2_reduce_kernel(
    const float* __restrict__ p0, const float* __restrict__ p1,
    const float* __restrict__ bias, const float* __restrict__ res,
    float* __restrict__ out)
{
    const int i = blockIdx.x * 256 + threadIdx.x;    // float4 index
    const float4 a = ((const float4*)p0)[i];
    const float4 b = ((const float4*)p1)[i];
    const float4 r = ((const float4*)res)[i];
    const float4 g = ((const float4*)bias)[i & 255]; // DIMM/4 = 256 float4/row
    float4 o;
    o.x = a.x + b.x + r.x + g.x;
    o.y = a.y + b.y + r.y + g.y;
    o.z = a.z + b.z + r.z + g.z;
    o.w = a.w + b.w + r.w + g.w;
    ((float4*)out)[i] = o;
}

// ---------------------------------------------------------------------------
// V transpose per head: qkv[b][n][2*DIMM + h*64 + d] -> vT[bh][d][n]
// ---------------------------------------------------------------------------
__global__ __launch_bounds__(256) void vtrans_kernel(
    const bf16* __restrict__ qkv, bf16* __restrict__ vT)
{
    __shared__ bf16 t[64 * 64];
    const int n0 = blockIdx.x * 64;
    const int bh = blockIdx.y;
    const int b = bh >> 4, h = bh & 15;
    const bf16* src = qkv + (size_t)(b * SEQ + n0) * QKV3 + 2 * DIMM + h * DHEAD;

    #pragma unroll
    for (int it = 0; it < 2; ++it) {
        const int c = it * 256 + threadIdx.x;   // 512 chunks of 8 elems
        const int n = c >> 3, d8 = (c & 7) * 8;
        const bf16x8 v8 = *(const bf16x8*)(src + (size_t)n * QKV3 + d8);
        const int byte = (n * 128 + d8 * 2) ^ (((n >> 3) & 7) << 4);
        *(bf16x8*)((char*)t + byte) = v8;
    }
    __syncthreads();
    #pragma unroll
    for (int it = 0; it < 2; ++it) {
        const int c = it * 256 + threadIdx.x;
        const int d = c >> 3, nc = c & 7;
        bf16x8 o8;
        #pragma unroll
        for (int i = 0; i < 8; ++i) {
            const int n = nc * 8 + i;
            const int byte = (n * 128 + d * 2) ^ ((nc & 7) << 4);
            o8[i] = *(const bf16*)((const char*)t + byte);
        }
        *(bf16x8*)(vT + (size_t)bh * DHEAD * SEQ + (size_t)d * SEQ + n0 + nc * 8) = o8;
    }
}

// ---------------------------------------------------------------------------
// Flash attention v5: occupancy x2. Grid 1024 (32 qtiles of 64 rows x 32 bh),
// 4 blocks/CU (LDS 40KB), each wave owns 16 q-rows (single mf).
// Swapped-operand S^T/O^T structure, double-buffered K/V via global_load_lds
// (pre-swizzled source), bijective XCD swizzle, defer-max (T13), setprio (T5).
// ---------------------------------------------------------------------------
__global__ __launch_bounds__(256, 4)
void attn_kernel(const bf16* __restrict__ qkv, const bf16* __restrict__ vT,
                 bf16* __restrict__ out)
{
    __shared__ bf16 Ks[2][64 * 64];
    __shared__ bf16 Vs[2][64 * 64];
    __shared__ bf16 Ps[4][16 * 64];
    const int bid = blockIdx.x;                    // 0..1023
    const int idx = (bid & 7) * 128 + (bid >> 3);  // bijective XCD swizzle
    const int qt = idx & 31;
    const int bh = idx >> 5;                       // 4 bh per XCD chunk
    const int b = bh >> 4, h = bh & 15;
    const int tid = threadIdx.x;
    const int lane = tid & 63, wave = tid >> 6;
    const int q = lane & 15, hi = lane >> 4;

    const bf16* qbase = qkv + (size_t)(b * SEQ) * QKV3 + h * DHEAD;
    const bf16* kbase = qbase + DIMM;
    const bf16* vbase = vT + (size_t)bh * DHEAD * SEQ;

    // Q fragment (B operand: col q, k-slots hi*8+j), scale 1/8 folded in
    const int q0 = qt * 64 + wave * 16;
    bf16x8 qf[2];
    {
        const bf16* qp = qbase + (size_t)(q0 + q) * QKV3 + (hi << 3);
        qf[0] = *(const bf16x8*)qp;
        qf[1] = *(const bf16x8*)(qp + 32);
        #pragma unroll
        for (int j = 0; j < 8; ++j) {
            qf[0][j] = (bf16)((float)qf[0][j] * 0.125f);
            qf[1][j] = (bf16)((float)qf[1][j] * 0.125f);
        }
    }

    // staging: wave stages LDS elems [wave*1024, +1024); pre-swizzled source
    const int srow = lane >> 3;
    const int scol = ((lane & 7) ^ srow) << 3;
    const bf16* gk = kbase + (size_t)(wave * 16 + srow) * QKV3 + scol;
    const bf16* gv = vbase + (size_t)(wave * 16 + srow) * SEQ + scol;

#define STAGE(BUF, KT) do {                                        \
        bf16* lk_ = &Ks[BUF][wave * 1024];                         \
        bf16* lv_ = &Vs[BUF][wave * 1024];                         \
        GLDS16(gk + (size_t)(KT) * QKV3,       lk_);               \
        GLDS16(gk + (size_t)((KT) + 8) * QKV3, lk_ + 512);         \
        GLDS16(gv + (KT),                      lv_);               \
        GLDS16(gv + (KT) + 8 * SEQ,            lv_ + 512);         \
    } while (0)

    float m = -1e30f, l = 0.0f;
    f32x4 o[4] = {};

    STAGE(0, 0);
    int cur = 0;
    for (int kt = 0; kt < SEQ; kt += 64) {
        __syncthreads();   // drains vmcnt(0): STAGE(kt) resident; buf cur^1 free
        if (kt + 64 < SEQ) STAGE(cur ^ 1, kt + 64);   // fire-and-forget

        // S^T = K Q^T : sv[kf][r] = S[kv=kf*16+hi*4+r][q]
        f32x4 sv[4];
        __builtin_amdgcn_s_setprio(1);
        #pragma unroll
        for (int kf = 0; kf < 4; ++kf) {
            f32x4 z = {0.f, 0.f, 0.f, 0.f};
            sv[kf] = z;
            #pragma unroll
            for (int ks = 0; ks < 2; ++ks) {
                const int row = kf * 16 + q;
                const int bo = (row * 128 + ks * 64 + (hi << 4)) ^ ((row & 7) << 4);
                const bf16x8 kfrag = *(const bf16x8*)((const char*)&Ks[cur][0] + bo);
                sv[kf] = mfma16(kfrag, qf[ks], sv[kf]);
            }
        }
        __builtin_amdgcn_s_setprio(0);

        // in-register row max (16 values) + 2 shfl across hi-groups
        float pmax;
        {
            float a = fmaxf(fmaxf(sv[0][0], sv[0][1]), fmaxf(sv[0][2], sv[0][3]));
            float b2 = fmaxf(fmaxf(sv[1][0], sv[1][1]), fmaxf(sv[1][2], sv[1][3]));
            float c = fmaxf(fmaxf(sv[2][0], sv[2][1]), fmaxf(sv[2][2], sv[2][3]));
            float d = fmaxf(fmaxf(sv[3][0], sv[3][1]), fmaxf(sv[3][2], sv[3][3]));
            pmax = fmaxf(fmaxf(a, b2), fmaxf(c, d));
        }
        pmax = fmaxf(pmax, __shfl_xor(pmax, 16, 64));
        pmax = fmaxf(pmax, __shfl_xor(pmax, 32, 64));

        // defer-max (THR=8)
        if (__any(pmax - m > 8.0f)) {
            const float nm = fmaxf(m, pmax);
            const float fr = __expf(m - nm);
            l *= fr;
            #pragma unroll
            for (int df = 0; df < 4; ++df) {
                o[df][0] *= fr; o[df][1] *= fr;
                o[df][2] *= fr; o[df][3] *= fr;
            }
            m = nm;
        }

        // P = exp(S - m): pack 4 bf16 -> one b64 write per kf
        float rsum = 0.0f;
        #pragma unroll
        for (int kf = 0; kf < 4; ++kf) {
            float p0 = __expf(sv[kf][0] - m);
            float p1 = __expf(sv[kf][1] - m);
            float p2 = __expf(sv[kf][2] - m);
            float p3 = __expf(sv[kf][3] - m);
            rsum += (p0 + p1) + (p2 + p3);
            bf16x4 pk = { (bf16)p0, (bf16)p1, (bf16)p2, (bf16)p3 };
            const int bo = (q * 128 + kf * 32 + hi * 8) ^ ((q & 7) << 4);
            *(bf16x4*)((char*)Ps[wave] + bo) = pk;
        }
        rsum += __shfl_xor(rsum, 16, 64);
        rsum += __shfl_xor(rsum, 32, 64);
        l += rsum;

        // P B-fragments: col q, kv-slots ks*32 + hi*8 + j
        bf16x8 pf[2];
        #pragma unroll
        for (int ks = 0; ks < 2; ++ks) {
            const int bo = (q * 128 + ks * 64 + (hi << 4)) ^ ((q & 7) << 4);
            pf[ks] = *(const bf16x8*)((const char*)Ps[wave] + bo);
        }
        // O^T += V^T P^T : o[df] has col q, rows d = df*16 + hi*4 + r
        __builtin_amdgcn_s_setprio(1);
        #pragma unroll
        for (int df = 0; df < 4; ++df)
            #pragma unroll
            for (int ks = 0; ks < 2; ++ks) {
                const int rowv = df * 16 + q;
                const int bo = (rowv * 128 + ks * 64 + (hi << 4)) ^ ((rowv & 7) << 4);
                const bf16x8 vfrag = *(const bf16x8*)((const char*)&Vs[cur][0] + bo);
                o[df] = mfma16(vfrag, pf[ks], o[df]);
            }
        __builtin_amdgcn_s_setprio(0);
        cur ^= 1;
    }
#undef STAGE

    // epilogue: normalize, pack 4 bf16 (consecutive d) per 8B store
    {
        const float inv = 1.0f / l;
        const int grow = b * SEQ + q0 + q;
        #pragma unroll
        for (int df = 0; df < 4; ++df) {
            bf16x4 pk = { (bf16)(o[df][0] * inv), (bf16)(o[df][1] * inv),
                          (bf16)(o[df][2] * inv), (bf16)(o[df][3] * inv) };
            *(bf16x4*)(out + (size_t)grow * DIMM + h * DHEAD + df * 16 + hi * 4) = pk;
        }
    }
}

// ---------------------------------------------------------------------------
extern "C" void kernel_launch(void* const* d_in, const int* in_sizes, int n_in,
                              void* d_out, int out_size, void* d_ws, size_t ws_size,
                              hipStream_t stream)
{
    (void)in_sizes; (void)n_in; (void)out_size;
    const float* x    = (const float*)d_in[0];
    const float* ln1g = (const float*)d_in[1];
    const float* ln1b = (const float*)d_in[2];
    const float* ln2g = (const float*)d_in[3];
    const float* ln2b = (const float*)d_in[4];
    const float* wqkv = (const float*)d_in[5];
    const float* wout = (const float*)d_in[6];
    const float* bout = (const float*)d_in[7];
    const float* wff1 = (const float*)d_in[8];
    const float* bff1 = (const float*)d_in[9];
    const float* wff2 = (const float*)d_in[10];
    const float* bff2 = (const float*)d_in[11];

    char* ws = (char*)d_ws;
    const dim3 blk(256);
    const bool splitk = ws_size >= 92274688ULL;   // 88 MB packed layout

    if (splitk) {
        // Phase-lifetime-packed layout (all live ranges disjoint; 88 MB):
        bf16*  wff2T = (bf16*)(ws);
        bf16*  woutT = (bf16*)(ws + 8388608);
        bf16*  wff1T = (bf16*)(ws + 10485760);
        bf16*  wqkvT = (bf16*)(ws + 18874368);
        bf16*  hbuf  = (bf16*)(ws + 25165824);
        bf16*  qkvb  = (bf16*)(ws + 33554432);
        bf16*  vT    = (bf16*)(ws + 58720256);
        bf16*  attnb = (bf16*)(ws + 67108864);
        float* x2    = (float*)(ws + 75497472);
        bf16*  fbuf  = (bf16*)(ws + 41943040);
        float* p0    = (float*)(ws + 8388608);
        float* p1    = (float*)(ws + 25165824);

        tcast_kernel<<<dim3(QKV3 / 32, DIMM / 32), blk, 0, stream>>>(wqkv, wqkvT, DIMM, QKV3);
        tcast_kernel<<<dim3(DIMM / 32, DIMM / 32), blk, 0, stream>>>(wout, woutT, DIMM, DIMM);
        tcast_kernel<<<dim3(FFD  / 32, DIMM / 32), blk, 0, stream>>>(wff1, wff1T, DIMM, FFD);
        tcast_kernel<<<dim3(DIMM / 32, FFD  / 32), blk, 0, stream>>>(wff2, wff2T, FFD, DIMM);

        ln_cast_kernel<<<NROWS, blk, 0, stream>>>(x, ln1g, ln1b, hbuf);
        gemm_bt_kernel<0><<<(NROWS / 128) * (QKV3 / 128), blk, 0, stream>>>(
            hbuf, wqkvT, nullptr, nullptr, qkvb, NROWS, QKV3, DIMM, DIMM);
        vtrans_kernel<<<dim3(SEQ / 64, BATCH * NHEAD), blk, 0, stream>>>(qkvb, vT);
        attn_kernel<<<dim3(1024), blk, 0, stream>>>(qkvb, vT, attnb);
        gemm_bt_kernel<1><<<(NROWS / 128) * (DIMM / 128), blk, 0, stream>>>(
            attnb, woutT, bout, x, x2, NROWS, DIMM, DIMM, DIMM);
        ln_cast_kernel<<<NROWS, blk, 0, stream>>>(x2, ln2g, ln2b, hbuf);
        gemm_bt_kernel<2><<<(NROWS / 128) * (FFD / 128), blk, 0, stream>>>(
            hbuf, wff1T, bff1, nullptr, fbuf, NROWS, FFD, DIMM, DIMM);
        gemm_bt_kernel<3><<<2 * (NROWS / 128) * (DIMM / 128), blk, 0, stream>>>(
            fbuf, wff2T, nullptr, (const float*)p1, p0, NROWS, DIMM, FFD / 2, FFD);
        ff2_reduce_kernel<<<(NROWS * DIMM) / 1024, blk, 0, stream>>>(
            p0, p1, bff2, x2, (float*)d_out);
    } else {
        // Fallback: round-4 proven layout, single-pass FF2.
        bf16*  wqkvT = (bf16*)(ws);
        bf16*  woutT = (bf16*)(ws + 6291456);
        bf16*  wff1T = (bf16*)(ws + 8388608);
        bf16*  wff2T = (bf16*)(ws + 16777216);
        float* x2    = (float*)(ws + 25165824);
        bf16*  vT    = (bf16*)(ws + 25165824);
        bf16*  hbuf  = (bf16*)(ws + 41943040);
        bf16*  qkvb  = (bf16*)(ws + 50331648);
        bf16*  attnb = (bf16*)(ws + 75497472);
        bf16*  fbuf  = (bf16*)(ws + 50331648);

        tcast_kernel<<<dim3(QKV3 / 32, DIMM / 32), blk, 0, stream>>>(wqkv, wqkvT, DIMM, QKV3);
        tcast_kernel<<<dim3(DIMM / 32, DIMM / 32), blk, 0, stream>>>(wout, woutT, DIMM, DIMM);
        tcast_kernel<<<dim3(FFD  / 32, DIMM / 32), blk, 0, stream>>>(wff1, wff1T, DIMM, FFD);
        tcast_kernel<<<dim3(DIMM / 32, FFD  / 32), blk, 0, stream>>>(wff2, wff2T, FFD, DIMM);

        ln_cast_kernel<<<NROWS, blk, 0, stream>>>(x, ln1g, ln1b, hbuf);
        gemm_bt_kernel<0><<<(NROWS / 128) * (QKV3 / 128), blk, 0, stream>>>(
            hbuf, wqkvT, nullptr, nullptr, qkvb, NROWS, QKV3, DIMM, DIMM);
        vtrans_kernel<<<dim3(SEQ / 64, BATCH * NHEAD), blk, 0, stream>>>(qkvb, vT);
        attn_kernel<<<dim3(1024), blk, 0, stream>>>(qkvb, vT, attnb);
        gemm_bt_kernel<1><<<(NROWS / 128) * (DIMM / 128), blk, 0, stream>>>(
            attnb, woutT, bout, x, x2, NROWS, DIMM, DIMM, DIMM);
        ln_cast_kernel<<<NROWS, blk, 0, stream>>>(x2, ln2g, ln2b, hbuf);
        gemm_bt_kernel<2><<<(NROWS / 128) * (FFD / 128), blk, 0, stream>>>(
            hbuf, wff1T, bff1, nullptr, fbuf, NROWS, FFD, DIMM, DIMM);
        gemm_bt_kernel<1><<<(NROWS / 128) * (DIMM / 128), blk, 0, stream>>>(
            fbuf, wff2T, bff2, x2, (float*)d_out, NROWS, DIMM, FFD, FFD);
    }
}